// Round 1
// baseline (1272.339 us; speedup 1.0000x reference)
//
#include <hip/hip_runtime.h>
#include <math.h>

#define F_IN 128
#define F_HID 64

// ---------------- init: deg=1 (self loop), dw=0, maxbits=0 ----------------
__global__ void k_init(float* deg, float* dw, unsigned* maxbits, int N) {
  int i = blockIdx.x * blockDim.x + threadIdx.x;
  if (i < N) { deg[i] = 1.0f; dw[i] = 0.0f; }
  if (i == 0) *maxbits = 0u;
}

// ---------------- scatter: deg[dst]+=ew, dw[src]+=ew ----------------
__global__ void k_scatter_deg(const int* __restrict__ src, const int* __restrict__ dst,
                              const float* __restrict__ ew,
                              float* deg, float* dw, int E) {
  int e = blockIdx.x * blockDim.x + threadIdx.x;
  if (e < E) {
    float w = ew[e];
    atomicAdd(&deg[dst[e]], w);
    atomicAdd(&dw[src[e]], w);
  }
}

// ---------------- h0 = x @ W1  (wave per row, W1 in 128 VGPRs) ----------------
__global__ void k_gemm1(const float* __restrict__ x, const float* __restrict__ W1,
                        float* __restrict__ h0, int N) {
  int lane = threadIdx.x & 63;
  int wid = (blockIdx.x * blockDim.x + threadIdx.x) >> 6;
  int nw = (gridDim.x * blockDim.x) >> 6;
  float w[F_IN];
#pragma unroll
  for (int k = 0; k < F_IN; ++k) w[k] = W1[k * F_HID + lane];
  for (int i = wid; i < N; i += nw) {
    float xa = x[i * F_IN + lane];
    float xb = x[i * F_IN + 64 + lane];
    float acc0 = 0.f, acc1 = 0.f;
#pragma unroll
    for (int k = 0; k < 64; ++k) {
      float xk0 = __int_as_float(__builtin_amdgcn_readlane(__float_as_int(xa), k));
      float xk1 = __int_as_float(__builtin_amdgcn_readlane(__float_as_int(xb), k));
      acc0 = fmaf(xk0, w[k], acc0);
      acc1 = fmaf(xk1, w[64 + k], acc1);
    }
    h0[i * F_HID + lane] = acc0 + acc1;
  }
}

// ---------------- dinv = rsqrt(deg) in place; max(dw) ----------------
__global__ void k_dinv_max(float* deg_inout, const float* __restrict__ dw,
                           unsigned* maxbits, int N) {
  int i = blockIdx.x * blockDim.x + threadIdx.x;
  float v = 0.f;
  if (i < N) {
    deg_inout[i] = rsqrtf(deg_inout[i]);
    v = dw[i];
  }
  for (int m = 32; m; m >>= 1) v = fmaxf(v, __shfl_xor(v, m, 64));
  if ((threadIdx.x & 63) == 0) atomicMax(maxbits, __float_as_uint(v));
}

// ---------------- agg1 init with self-loop contribution ----------------
__global__ void k_selfinit(const float* __restrict__ h0, const float* __restrict__ dinv,
                           float* __restrict__ agg1, int N) {
  int t = blockIdx.x * blockDim.x + threadIdx.x;
  if (t < N * F_HID) {
    int i = t >> 6;
    float di = dinv[i];
    agg1[t] = h0[t] * (di * di);
  }
}

// ---------------- edge aggregation, layer 1 (wave per edge) ----------------
__global__ void k_edge_agg1(const int* __restrict__ src, const int* __restrict__ dst,
                            const float* __restrict__ ew, const float* __restrict__ dinv,
                            const float* __restrict__ h0, float* agg1, int E) {
  int lane = threadIdx.x & 63;
  int wid = (blockIdx.x * blockDim.x + threadIdx.x) >> 6;
  int nw = (gridDim.x * blockDim.x) >> 6;
  for (int e = wid; e < E; e += nw) {
    int s = src[e], d = dst[e];
    float norm = dinv[s] * ew[e] * dinv[d];
    atomicAdd(&agg1[d * F_HID + lane], h0[s * F_HID + lane] * norm);
  }
}

// ------- layer1 finish: h=relu(agg1+b1); s=h.W2; agg2 init (self loop) -------
__global__ void k_finish1(const float* __restrict__ agg1, const float* __restrict__ b1,
                          const float* __restrict__ W2, const float* __restrict__ dinv,
                          float* __restrict__ s_out, float* __restrict__ agg2, int N) {
  int lane = threadIdx.x & 63;
  int i = (blockIdx.x * blockDim.x + threadIdx.x) >> 6;
  if (i >= N) return;
  float h = fmaxf(agg1[i * F_HID + lane] + b1[lane], 0.f);
  float p = h * W2[lane];
  for (int m = 32; m; m >>= 1) p += __shfl_xor(p, m, 64);
  if (lane == 0) {
    s_out[i] = p;
    float di = dinv[i];
    agg2[i] = p * (di * di);
  }
}

// ---------------- edge aggregation, layer 2 (scalar per edge) ----------------
__global__ void k_edge_agg2(const int* __restrict__ src, const int* __restrict__ dst,
                            const float* __restrict__ ew, const float* __restrict__ dinv,
                            const float* __restrict__ s_in, float* agg2, int E) {
  int e = blockIdx.x * blockDim.x + threadIdx.x;
  if (e < E) {
    int s = src[e], d = dst[e];
    atomicAdd(&agg2[d], s_in[s] * dinv[s] * ew[e] * dinv[d]);
  }
}

// ---------------- final: sigmoid + degree-weighted score ----------------
__global__ void k_final(const float* __restrict__ agg2, const float* __restrict__ b2,
                        const float* __restrict__ dw, const unsigned* __restrict__ maxbits,
                        float* __restrict__ out, int N) {
  int i = blockIdx.x * blockDim.x + threadIdx.x;
  if (i < N) {
    float md = __uint_as_float(*maxbits);
    float z = agg2[i] + b2[0];
    float sc = 1.0f / (1.0f + expf(-z));
    out[i] = sc * (1.0f + dw[i] / md);
  }
}

extern "C" void kernel_launch(void* const* d_in, const int* in_sizes, int n_in,
                              void* d_out, int out_size, void* d_ws, size_t ws_size,
                              hipStream_t stream) {
  const float* x  = (const float*)d_in[0];
  const int*   ei = (const int*)d_in[1];
  const float* ew = (const float*)d_in[2];
  const float* W1 = (const float*)d_in[3];
  const float* b1 = (const float*)d_in[4];
  const float* W2 = (const float*)d_in[5];
  const float* b2 = (const float*)d_in[6];
  float* out = (float*)d_out;

  int N = out_size;      // 100000
  int E = in_sizes[2];   // 3200000
  const int* src = ei;
  const int* dst = ei + E;

  float* ws   = (float*)d_ws;
  float* h0   = ws;                       // N*64
  float* agg1 = h0 + (size_t)N * F_HID;   // N*64
  float* deg  = agg1 + (size_t)N * F_HID; // N (becomes dinv in place)
  float* dw   = deg + N;                  // N
  float* sarr = dw + N;                   // N
  float* agg2 = sarr + N;                 // N
  unsigned* maxbits = (unsigned*)(agg2 + N);

  k_init<<<(N + 255) / 256, 256, 0, stream>>>(deg, dw, maxbits, N);
  k_scatter_deg<<<(E + 255) / 256, 256, 0, stream>>>(src, dst, ew, deg, dw, E);
  k_gemm1<<<1024, 256, 0, stream>>>(x, W1, h0, N);
  k_dinv_max<<<(N + 255) / 256, 256, 0, stream>>>(deg, dw, maxbits, N);
  k_selfinit<<<(N * F_HID + 255) / 256, 256, 0, stream>>>(h0, deg, agg1, N);
  k_edge_agg1<<<32768, 256, 0, stream>>>(src, dst, ew, deg, h0, agg1, E);
  k_finish1<<<(N * F_HID + 255) / 256, 256, 0, stream>>>(agg1, b1, W2, deg, sarr, agg2, N);
  k_edge_agg2<<<(E + 255) / 256, 256, 0, stream>>>(src, dst, ew, deg, sarr, agg2, E);
  k_final<<<(N + 255) / 256, 256, 0, stream>>>(agg2, b2, dw, maxbits, out, N);
}

// Round 2
// 1010.760 us; speedup vs baseline: 1.2588x; 1.2588x over previous
//
#include <hip/hip_runtime.h>
#include <math.h>

#define F_IN 128
#define F_HID 64

// ---------------- init: deg=1 (self loop), dw=0, cnt=0, maxbits=0 ----------------
__global__ void k_init(float* deg, float* dw, int* cnt, unsigned* maxbits, int N) {
  int i = blockIdx.x * blockDim.x + threadIdx.x;
  if (i < N) { deg[i] = 1.0f; dw[i] = 0.0f; cnt[i] = 0; }
  if (i == 0) *maxbits = 0u;
}

// ---------------- histogram: deg[dst]+=ew, dw[src]+=ew, cnt[dst]++ ----------------
__global__ void k_hist(const int* __restrict__ src, const int* __restrict__ dst,
                       const float* __restrict__ ew,
                       float* deg, float* dw, int* cnt, int E) {
  int e = blockIdx.x * blockDim.x + threadIdx.x;
  if (e < E) {
    int d = dst[e];
    float w = ew[e];
    atomicAdd(&deg[d], w);
    atomicAdd(&dw[src[e]], w);
    atomicAdd(&cnt[d], 1);
  }
}

// ---------------- h0 = x @ W1  (wave per row, W1 in 128 VGPRs) ----------------
__global__ void k_gemm1(const float* __restrict__ x, const float* __restrict__ W1,
                        float* __restrict__ h0, int N) {
  int lane = threadIdx.x & 63;
  int wid = (blockIdx.x * blockDim.x + threadIdx.x) >> 6;
  int nw = (gridDim.x * blockDim.x) >> 6;
  float w[F_IN];
#pragma unroll
  for (int k = 0; k < F_IN; ++k) w[k] = W1[k * F_HID + lane];
  for (int i = wid; i < N; i += nw) {
    float xa = x[i * F_IN + lane];
    float xb = x[i * F_IN + 64 + lane];
    float acc0 = 0.f, acc1 = 0.f;
#pragma unroll
    for (int k = 0; k < 64; ++k) {
      float xk0 = __int_as_float(__builtin_amdgcn_readlane(__float_as_int(xa), k));
      float xk1 = __int_as_float(__builtin_amdgcn_readlane(__float_as_int(xb), k));
      acc0 = fmaf(xk0, w[k], acc0);
      acc1 = fmaf(xk1, w[64 + k], acc1);
    }
    h0[i * F_HID + lane] = acc0 + acc1;
  }
}

// ---------------- dinv = rsqrt(deg) in place; max(dw) ----------------
__global__ void k_dinv_max(float* deg_inout, const float* __restrict__ dw,
                           unsigned* maxbits, int N) {
  int i = blockIdx.x * blockDim.x + threadIdx.x;
  float v = 0.f;
  if (i < N) {
    deg_inout[i] = rsqrtf(deg_inout[i]);
    v = dw[i];
  }
  for (int m = 32; m; m >>= 1) v = fmaxf(v, __shfl_xor(v, m, 64));
  if ((threadIdx.x & 63) == 0) atomicMax(maxbits, __float_as_uint(v));
}

// ---------------- scan A: per-256-block exclusive scan of cnt ----------------
__global__ void k_scanA(const int* __restrict__ cnt, int* __restrict__ off,
                        int* __restrict__ partials, int N) {
  __shared__ int lds[256];
  int tid = threadIdx.x;
  int g = blockIdx.x * 256 + tid;
  int v = (g < N) ? cnt[g] : 0;
  lds[tid] = v; __syncthreads();
  for (int o = 1; o < 256; o <<= 1) {
    int t = (tid >= o) ? lds[tid - o] : 0;
    __syncthreads();
    lds[tid] += t;
    __syncthreads();
  }
  if (g < N) off[g] = lds[tid] - v;            // exclusive within block
  if (tid == 255) partials[blockIdx.x] = lds[255];  // block total
}

// ---------------- scan B: single-block exclusive scan of partials ----------------
__global__ void k_scanB(int* partials, int nb) {
  __shared__ int lds[1024];
  int tid = threadIdx.x;
  int v = (tid < nb) ? partials[tid] : 0;
  lds[tid] = v; __syncthreads();
  for (int o = 1; o < 1024; o <<= 1) {
    int t = (tid >= o) ? lds[tid - o] : 0;
    __syncthreads();
    lds[tid] += t;
    __syncthreads();
  }
  if (tid < nb) partials[tid] = lds[tid] - v;  // exclusive
}

// ---------------- scan C: finalize offsets, init cursors ----------------
__global__ void k_scanC(int* __restrict__ off, int* __restrict__ cursor,
                        const int* __restrict__ partials, int N, int E) {
  int g = blockIdx.x * blockDim.x + threadIdx.x;
  if (g < N) {
    int o = off[g] + partials[g >> 8];
    off[g] = o;
    cursor[g] = o;
  }
  if (g == 0) off[N] = E;
}

// ---------------- scatter edges into dst-CSR, premultiplied norm ----------------
__global__ void k_scatter(const int* __restrict__ src, const int* __restrict__ dst,
                          const float* __restrict__ ew, const float* __restrict__ dinv,
                          int* cursor, int* __restrict__ csr_src,
                          float* __restrict__ csr_w, int E) {
  int e = blockIdx.x * blockDim.x + threadIdx.x;
  if (e < E) {
    int s = src[e], d = dst[e];
    int p = atomicAdd(&cursor[d], 1);
    csr_src[p] = s;
    csr_w[p] = dinv[s] * ew[e] * dinv[d];
  }
}

// ------ layer-1 aggregation: wave per node, reg accumulate; fused relu+b1+.W2 ------
__global__ void k_node_agg1(const float* __restrict__ h0, const float* __restrict__ dinv,
                            const int* __restrict__ off, const int* __restrict__ csr_src,
                            const float* __restrict__ csr_w, const float* __restrict__ b1,
                            const float* __restrict__ W2, float* __restrict__ sarr, int N) {
  int lane = threadIdx.x & 63;
  int i = (blockIdx.x * blockDim.x + threadIdx.x) >> 6;
  if (i >= N) return;
  float di = dinv[i];
  float acc = h0[(size_t)i * F_HID + lane] * di * di;   // self loop
  int p0 = off[i], p1 = off[i + 1];
  for (int p = p0; p < p1; p += 64) {
    int rem = p1 - p;
    int m = rem < 64 ? rem : 64;
    int sj = 0; float wj = 0.f;
    if (lane < m) { sj = csr_src[p + lane]; wj = csr_w[p + lane]; }
    for (int j = 0; j < m; ++j) {
      int s = __builtin_amdgcn_readlane(sj, j);
      float w = __int_as_float(__builtin_amdgcn_readlane(__float_as_int(wj), j));
      acc = fmaf(h0[(size_t)s * F_HID + lane], w, acc);
    }
  }
  float h = fmaxf(acc + b1[lane], 0.f);
  float pdt = h * W2[lane];
  for (int mm = 32; mm; mm >>= 1) pdt += __shfl_xor(pdt, mm, 64);
  if (lane == 0) sarr[i] = pdt;
}

// ------ layer-2 aggregation + final: wave per node, lanes stride edges ------
__global__ void k_agg2_final(const float* __restrict__ sarr, const float* __restrict__ dinv,
                             const int* __restrict__ off, const int* __restrict__ csr_src,
                             const float* __restrict__ csr_w, const float* __restrict__ b2,
                             const float* __restrict__ dw, const unsigned* __restrict__ maxbits,
                             float* __restrict__ out, int N) {
  int lane = threadIdx.x & 63;
  int i = (blockIdx.x * blockDim.x + threadIdx.x) >> 6;
  if (i >= N) return;
  float di = dinv[i];
  float acc = (lane == 0) ? sarr[i] * di * di : 0.f;    // self loop
  int p0 = off[i], p1 = off[i + 1];
  for (int p = p0 + lane; p < p1; p += 64)
    acc = fmaf(csr_w[p], sarr[csr_src[p]], acc);
  for (int mm = 32; mm; mm >>= 1) acc += __shfl_xor(acc, mm, 64);
  if (lane == 0) {
    float md = __uint_as_float(*maxbits);
    float z = acc + b2[0];
    float sc = 1.0f / (1.0f + expf(-z));
    out[i] = sc * (1.0f + dw[i] / md);
  }
}

extern "C" void kernel_launch(void* const* d_in, const int* in_sizes, int n_in,
                              void* d_out, int out_size, void* d_ws, size_t ws_size,
                              hipStream_t stream) {
  const float* x  = (const float*)d_in[0];
  const int*   ei = (const int*)d_in[1];
  const float* ew = (const float*)d_in[2];
  const float* W1 = (const float*)d_in[3];
  const float* b1 = (const float*)d_in[4];
  const float* W2 = (const float*)d_in[5];
  const float* b2 = (const float*)d_in[6];
  float* out = (float*)d_out;

  int N = out_size;      // 100000
  int E = in_sizes[2];   // 3200000
  const int* src = ei;
  const int* dst = ei + E;
  int NB = (N + 255) / 256;   // scan blocks (<=1024)

  float* ws   = (float*)d_ws;
  float* h0      = ws;                         // N*64 f
  float* deg     = h0 + (size_t)N * F_HID;     // N f (becomes dinv)
  float* dw      = deg + N;                    // N f
  float* sarr    = dw + N;                     // N f
  int*   cnt     = (int*)(sarr + N);           // N i
  int*   off     = cnt + N;                    // N+1 i
  int*   cursor  = off + N + 1;                // N i
  int*   partials= cursor + N;                 // 1024 i
  unsigned* maxbits = (unsigned*)(partials + 1024); // 1 u
  int*   csr_src = (int*)(maxbits + 1);        // E i
  float* csr_w   = (float*)(csr_src + E);      // E f

  k_init<<<(N + 255) / 256, 256, 0, stream>>>(deg, dw, cnt, maxbits, N);
  k_hist<<<(E + 255) / 256, 256, 0, stream>>>(src, dst, ew, deg, dw, cnt, E);
  k_gemm1<<<1024, 256, 0, stream>>>(x, W1, h0, N);
  k_dinv_max<<<(N + 255) / 256, 256, 0, stream>>>(deg, dw, maxbits, N);
  k_scanA<<<NB, 256, 0, stream>>>(cnt, off, partials, N);
  k_scanB<<<1, 1024, 0, stream>>>(partials, NB);
  k_scanC<<<NB, 256, 0, stream>>>(off, cursor, partials, N, E);
  k_scatter<<<(E + 255) / 256, 256, 0, stream>>>(src, dst, ew, deg, cursor, csr_src, csr_w, E);
  k_node_agg1<<<(N * 64 + 255) / 256, 256, 0, stream>>>(h0, deg, off, csr_src, csr_w, b1, W2, sarr, N);
  k_agg2_final<<<(N * 64 + 255) / 256, 256, 0, stream>>>(sarr, deg, off, csr_src, csr_w, b2, dw, maxbits, out, N);
}

// Round 3
// 678.377 us; speedup vs baseline: 1.8756x; 1.4900x over previous
//
#include <hip/hip_runtime.h>
#include <hip/hip_fp16.h>
#include <math.h>

#define F_IN 128
#define F_HID 64

// ---------------- init: cnt=0, dw=0, maxbits=0 ----------------
__global__ void k_init(int* cnt, float* dw, unsigned* maxbits, int N) {
  int i = blockIdx.x * blockDim.x + threadIdx.x;
  if (i < N) { cnt[i] = 0; dw[i] = 0.0f; }
  if (i == 0) *maxbits = 0u;
}

// ------- hist: rank[e] = old cnt[dst]++, dw[src]+=ew  (2 atomics/edge) -------
__global__ void k_hist2(const int* __restrict__ src, const int* __restrict__ dst,
                        const float* __restrict__ ew,
                        int* cnt, float* dw, int* __restrict__ rank, int E) {
  int e = blockIdx.x * blockDim.x + threadIdx.x;
  if (e < E) {
    rank[e] = atomicAdd(&cnt[dst[e]], 1);
    atomicAdd(&dw[src[e]], ew[e]);
  }
}

// ---------------- scan A: per-256-block exclusive scan of cnt ----------------
__global__ void k_scanA(const int* __restrict__ cnt, int* __restrict__ off,
                        int* __restrict__ partials, int N) {
  __shared__ int lds[256];
  int tid = threadIdx.x;
  int g = blockIdx.x * 256 + tid;
  int v = (g < N) ? cnt[g] : 0;
  lds[tid] = v; __syncthreads();
  for (int o = 1; o < 256; o <<= 1) {
    int t = (tid >= o) ? lds[tid - o] : 0;
    __syncthreads();
    lds[tid] += t;
    __syncthreads();
  }
  if (g < N) off[g] = lds[tid] - v;
  if (tid == 255) partials[blockIdx.x] = lds[255];
}

// ---------------- scan B: single-block exclusive scan of partials ----------------
__global__ void k_scanB(int* partials, int nb) {
  __shared__ int lds[1024];
  int tid = threadIdx.x;
  int v = (tid < nb) ? partials[tid] : 0;
  lds[tid] = v; __syncthreads();
  for (int o = 1; o < 1024; o <<= 1) {
    int t = (tid >= o) ? lds[tid - o] : 0;
    __syncthreads();
    lds[tid] += t;
    __syncthreads();
  }
  if (tid < nb) partials[tid] = lds[tid] - v;
}

// ---------------- scan C: finalize offsets ----------------
__global__ void k_scanC(int* __restrict__ off, const int* __restrict__ partials,
                        int N, int E) {
  int g = blockIdx.x * blockDim.x + threadIdx.x;
  if (g < N) off[g] = off[g] + partials[g >> 8];
  if (g == 0) off[N] = E;
}

// ------- scatter: atomic-free packed CSR write via precomputed rank -------
__global__ void k_scatter2(const int* __restrict__ src, const int* __restrict__ dst,
                           const float* __restrict__ ew, const int* __restrict__ rank,
                           const int* __restrict__ off, int2* __restrict__ csr, int E) {
  int e = blockIdx.x * blockDim.x + threadIdx.x;
  if (e < E) {
    int p = off[dst[e]] + rank[e];
    csr[p] = make_int2(src[e], __float_as_int(ew[e]));
  }
}

// ------- deg from CSR: dinv[i] = rsqrt(1 + sum of raw ew over row) -------
__global__ void k_deg_dinv(const int2* __restrict__ csr, const int* __restrict__ off,
                           float* __restrict__ dinv, int N) {
  int lane = threadIdx.x & 63;
  int i = (blockIdx.x * blockDim.x + threadIdx.x) >> 6;
  if (i >= N) return;
  int p0 = off[i], p1 = off[i + 1];
  float s = 0.f;
  for (int p = p0 + lane; p < p1; p += 64) s += __int_as_float(csr[p].y);
  for (int m = 32; m; m >>= 1) s += __shfl_xor(s, m, 64);
  if (lane == 0) dinv[i] = rsqrtf(1.0f + s);
}

// ---------------- max(dw) ----------------
__global__ void k_max(const float* __restrict__ dw, unsigned* maxbits, int N) {
  int i = blockIdx.x * blockDim.x + threadIdx.x;
  float v = (i < N) ? dw[i] : 0.f;
  for (int m = 32; m; m >>= 1) v = fmaxf(v, __shfl_xor(v, m, 64));
  if ((threadIdx.x & 63) == 0) atomicMax(maxbits, __float_as_uint(v));
}

// ------- g0 = dinv[i] * (x @ W1) row, stored fp16 (wave per row) -------
__global__ void k_gemm1(const float* __restrict__ x, const float* __restrict__ W1,
                        const float* __restrict__ dinv, __half* __restrict__ g0, int N) {
  int lane = threadIdx.x & 63;
  int wid = (blockIdx.x * blockDim.x + threadIdx.x) >> 6;
  int nw = (gridDim.x * blockDim.x) >> 6;
  float w[F_IN];
#pragma unroll
  for (int k = 0; k < F_IN; ++k) w[k] = W1[k * F_HID + lane];
  for (int i = wid; i < N; i += nw) {
    float xa = x[(size_t)i * F_IN + lane];
    float xb = x[(size_t)i * F_IN + 64 + lane];
    float acc0 = 0.f, acc1 = 0.f;
#pragma unroll
    for (int k = 0; k < 64; ++k) {
      float xk0 = __int_as_float(__builtin_amdgcn_readlane(__float_as_int(xa), k));
      float xk1 = __int_as_float(__builtin_amdgcn_readlane(__float_as_int(xb), k));
      acc0 = fmaf(xk0, w[k], acc0);
      acc1 = fmaf(xk1, w[64 + k], acc1);
    }
    g0[(size_t)i * F_HID + lane] = __float2half((acc0 + acc1) * dinv[i]);
  }
}

// ------- layer-1 agg: wave per node; fused relu+b1+·W2; sarr = dinv*(h·W2) -------
__global__ void k_agg1(const __half* __restrict__ g0, const float* __restrict__ dinv,
                       const int* __restrict__ off, const int2* __restrict__ csr,
                       const float* __restrict__ b1, const float* __restrict__ W2,
                       float* __restrict__ sarr, int N) {
  int lane = threadIdx.x & 63;
  int i = (blockIdx.x * blockDim.x + threadIdx.x) >> 6;
  if (i >= N) return;
  float acc = __half2float(g0[(size_t)i * F_HID + lane]);   // self (dinv-scaled)
  int p0 = off[i], p1 = off[i + 1];
  for (int p = p0; p < p1; p += 64) {
    int rem = p1 - p;
    int m = rem < 64 ? rem : 64;
    int2 ed = make_int2(0, 0);
    if (lane < m) ed = csr[p + lane];
    for (int j = 0; j < m; ++j) {
      int s = __builtin_amdgcn_readlane(ed.x, j);
      float w = __int_as_float(__builtin_amdgcn_readlane(ed.y, j));
      acc = fmaf(w, __half2float(g0[(size_t)s * F_HID + lane]), acc);
    }
  }
  float h = fmaxf(dinv[i] * acc + b1[lane], 0.f);
  float pdt = h * W2[lane];
  for (int mm = 32; mm; mm >>= 1) pdt += __shfl_xor(pdt, mm, 64);
  if (lane == 0) sarr[i] = dinv[i] * pdt;
}

// ------- layer-2 agg + final: z = dinv[i]*(t[i] + Σ ew·t[s]) + b2 -------
__global__ void k_agg2_final(const float* __restrict__ sarr, const float* __restrict__ dinv,
                             const int* __restrict__ off, const int2* __restrict__ csr,
                             const float* __restrict__ b2, const float* __restrict__ dw,
                             const unsigned* __restrict__ maxbits,
                             float* __restrict__ out, int N) {
  int lane = threadIdx.x & 63;
  int i = (blockIdx.x * blockDim.x + threadIdx.x) >> 6;
  if (i >= N) return;
  float acc = (lane == 0) ? sarr[i] : 0.f;     // self (t[i])
  int p0 = off[i], p1 = off[i + 1];
  for (int p = p0 + lane; p < p1; p += 64) {
    int2 ed = csr[p];
    acc = fmaf(__int_as_float(ed.y), sarr[ed.x], acc);
  }
  for (int mm = 32; mm; mm >>= 1) acc += __shfl_xor(acc, mm, 64);
  if (lane == 0) {
    float md = __uint_as_float(*maxbits);
    float z = dinv[i] * acc + b2[0];
    float sc = 1.0f / (1.0f + expf(-z));
    out[i] = sc * (1.0f + dw[i] / md);
  }
}

extern "C" void kernel_launch(void* const* d_in, const int* in_sizes, int n_in,
                              void* d_out, int out_size, void* d_ws, size_t ws_size,
                              hipStream_t stream) {
  const float* x  = (const float*)d_in[0];
  const int*   ei = (const int*)d_in[1];
  const float* ew = (const float*)d_in[2];
  const float* W1 = (const float*)d_in[3];
  const float* b1 = (const float*)d_in[4];
  const float* W2 = (const float*)d_in[5];
  const float* b2 = (const float*)d_in[6];
  float* out = (float*)d_out;

  int N = out_size;      // 100000
  int E = in_sizes[2];   // 3200000
  const int* src = ei;
  const int* dst = ei + E;
  int NB = (N + 255) / 256;   // scan blocks (<=1024)

  char* w8 = (char*)d_ws;
  int2*  csr   = (int2*)w8;                          // E int2 (8B aligned, first)
  __half* g0   = (__half*)(csr + E);                 // N*64 half
  float* dinv  = (float*)(g0 + (size_t)N * F_HID);   // N f
  float* dw    = dinv + N;                           // N f
  float* sarr  = dw + N;                             // N f
  int*   cnt   = (int*)(sarr + N);                   // N i
  int*   off   = cnt + N;                            // N+1 i
  int*   rank  = off + N + 1;                        // E i
  int*   partials = rank + E;                        // 1024 i
  unsigned* maxbits = (unsigned*)(partials + 1024);  // 1 u

  k_init<<<(N + 255) / 256, 256, 0, stream>>>(cnt, dw, maxbits, N);
  k_hist2<<<(E + 255) / 256, 256, 0, stream>>>(src, dst, ew, cnt, dw, rank, E);
  k_scanA<<<NB, 256, 0, stream>>>(cnt, off, partials, N);
  k_scanB<<<1, 1024, 0, stream>>>(partials, NB);
  k_scanC<<<NB, 256, 0, stream>>>(off, partials, N, E);
  k_scatter2<<<(E + 255) / 256, 256, 0, stream>>>(src, dst, ew, rank, off, csr, E);
  k_deg_dinv<<<(N * 64 + 255) / 256, 256, 0, stream>>>(csr, off, dinv, N);
  k_max<<<(N + 255) / 256, 256, 0, stream>>>(dw, maxbits, N);
  k_gemm1<<<1024, 256, 0, stream>>>(x, W1, dinv, g0, N);
  k_agg1<<<(N * 64 + 255) / 256, 256, 0, stream>>>(g0, dinv, off, csr, b1, W2, sarr, N);
  k_agg2_final<<<(N * 64 + 255) / 256, 256, 0, stream>>>(sarr, dinv, off, csr, b2, dw, maxbits, out, N);
}

// Round 4
// 494.619 us; speedup vs baseline: 2.5724x; 1.3715x over previous
//
#include <hip/hip_runtime.h>
#include <hip/hip_fp16.h>
#include <math.h>

#define F_IN 128
#define F_HID 64
#define NWG 512      // partition workgroups
#define BSH 7        // bucket shift (128 nodes per bucket)
#define BSZ 128
#define SEGCAP 6144  // max edges per bucket staged in LDS (mean 4096, ~45 sigma headroom)

// ---------------- g0 = x @ W1 (raw, fp16), wave per row, W1 in VGPRs ----------------
__global__ void k_gemm1(const float* __restrict__ x, const float* __restrict__ W1,
                        __half* __restrict__ g0, int N) {
  int lane = threadIdx.x & 63;
  int wid = (blockIdx.x * blockDim.x + threadIdx.x) >> 6;
  int nw = (gridDim.x * blockDim.x) >> 6;
  float w[F_IN];
#pragma unroll
  for (int k = 0; k < F_IN; ++k) w[k] = W1[k * F_HID + lane];
  for (int i = wid; i < N; i += nw) {
    float xa = x[(size_t)i * F_IN + lane];
    float xb = x[(size_t)i * F_IN + 64 + lane];
    float acc0 = 0.f, acc1 = 0.f;
#pragma unroll
    for (int k = 0; k < 64; ++k) {
      float xk0 = __int_as_float(__builtin_amdgcn_readlane(__float_as_int(xa), k));
      float xk1 = __int_as_float(__builtin_amdgcn_readlane(__float_as_int(xb), k));
      acc0 = fmaf(xk0, w[k], acc0);
      acc1 = fmaf(xk1, w[64 + k], acc1);
    }
    g0[(size_t)i * F_HID + lane] = __float2half(acc0 + acc1);
  }
}

// ------- P1: per-(bucket, wg) counts for dst-buckets and src-buckets (LDS only) -------
__global__ void k_count(const int* __restrict__ src, const int* __restrict__ dst,
                        int* __restrict__ cntAll, int NB, int E) {
  extern __shared__ int sh[];
  int* hD = sh;         // NB
  int* hS = sh + NB;    // NB
  int tid = threadIdx.x, w = blockIdx.x;
  for (int k = tid; k < 2 * NB; k += 256) sh[k] = 0;
  __syncthreads();
  int C = (E + NWG - 1) / NWG;
  int e0 = w * C, e1 = min(E, e0 + C);
  for (int e = e0 + tid; e < e1; e += 256) {
    atomicAdd(&hD[dst[e] >> BSH], 1);
    atomicAdd(&hS[src[e] >> BSH], 1);
  }
  __syncthreads();
  for (int b = tid; b < NB; b += 256) {
    cntAll[b * NWG + w] = hD[b];
    cntAll[(NB + b) * NWG + w] = hS[b];
  }
}

// ---------------- flat exclusive scan (in place), 1024-thread blocks ----------------
__global__ void k_scanA(int* __restrict__ data, int* __restrict__ partials, int TOT) {
  __shared__ int lds[1024];
  int tid = threadIdx.x;
  int g = blockIdx.x * 1024 + tid;
  int v = (g < TOT) ? data[g] : 0;
  lds[tid] = v; __syncthreads();
  for (int o = 1; o < 1024; o <<= 1) {
    int t = (tid >= o) ? lds[tid - o] : 0;
    __syncthreads();
    lds[tid] += t;
    __syncthreads();
  }
  if (g < TOT) data[g] = lds[tid] - v;
  if (tid == 1023) partials[blockIdx.x] = lds[1023];
}

__global__ void k_scanB(int* partials, int nb, unsigned* maxbits) {
  __shared__ int lds[1024];
  int tid = threadIdx.x;
  if (tid == 0) *maxbits = 0u;
  int v = (tid < nb) ? partials[tid] : 0;
  lds[tid] = v; __syncthreads();
  for (int o = 1; o < 1024; o <<= 1) {
    int t = (tid >= o) ? lds[tid - o] : 0;
    __syncthreads();
    lds[tid] += t;
    __syncthreads();
  }
  if (tid < nb) partials[tid] = lds[tid] - v;
}

__global__ void k_scanC(int* __restrict__ data, const int* __restrict__ partials, int TOT) {
  int g = blockIdx.x * 1024 + threadIdx.x;
  if (g < TOT) data[g] += partials[g >> 10];
}

// ------- P3: partition edges into dst-buckets (int2) and src-buckets (packed u32) -------
__global__ void k_part(const int* __restrict__ src, const int* __restrict__ dst,
                       const float* __restrict__ ew, const int* __restrict__ baseAll,
                       int2* __restrict__ gD, unsigned* __restrict__ gS, int NB, int E) {
  extern __shared__ int sh[];
  int* cD = sh;
  int* cS = sh + NB;
  int tid = threadIdx.x, w = blockIdx.x;
  for (int b = tid; b < NB; b += 256) {
    cD[b] = baseAll[b * NWG + w];
    cS[b] = baseAll[(NB + b) * NWG + w] - E;
  }
  __syncthreads();
  int C = (E + NWG - 1) / NWG;
  int e0 = w * C, e1 = min(E, e0 + C);
  for (int e = e0 + tid; e < e1; e += 256) {
    int s = src[e], d = dst[e];
    float wv = ew[e];
    int pD = atomicAdd(&cD[d >> BSH], 1);
    gD[pD] = make_int2(s | ((d & (BSZ - 1)) << 24), __float_as_int(wv));
    int pS = atomicAdd(&cS[s >> BSH], 1);
    unsigned hb = (unsigned)__half_as_ushort(__float2half(wv));
    gS[pS] = ((unsigned)(s & (BSZ - 1)) << 16) | hb;
  }
}

// ------- P4a: per-dst-bucket local counting sort -> CSR (in place) + off + dinv -------
__global__ void k_csr(int2* __restrict__ gD, const int* __restrict__ baseAll,
                      int* __restrict__ off, float* __restrict__ dinv,
                      int NB, int N, int E) {
  __shared__ int2 seg[SEGCAP];
  __shared__ int hist[BSZ];
  __shared__ int curs[BSZ];
  __shared__ float degf[BSZ];
  int tid = threadIdx.x, b = blockIdx.x;
  int bstart = baseAll[b * NWG];
  int bend = (b + 1 < NB) ? baseAll[(b + 1) * NWG] : E;
  int cnt = bend - bstart;
  for (int k = tid; k < cnt; k += 256) seg[k] = gD[bstart + k];
  if (tid < BSZ) { hist[tid] = 0; degf[tid] = 0.f; }
  __syncthreads();
  for (int k = tid; k < cnt; k += 256) {
    int dl = seg[k].x >> 24;
    atomicAdd(&hist[dl], 1);
    atomicAdd(&degf[dl], __int_as_float(seg[k].y));
  }
  __syncthreads();
  int v = (tid < BSZ) ? hist[tid] : 0;
  for (int o = 1; o < BSZ; o <<= 1) {
    int t = (tid < BSZ && tid >= o) ? hist[tid - o] : 0;
    __syncthreads();
    if (tid < BSZ) hist[tid] += t;
    __syncthreads();
  }
  if (tid < BSZ) {
    int excl = hist[tid] - v;
    curs[tid] = excl;
    int node = b * BSZ + tid;
    if (node < N) {
      off[node] = bstart + excl;
      dinv[node] = rsqrtf(1.0f + degf[tid]);
    }
  }
  if (b == NB - 1 && tid == 0) off[N] = E;
  __syncthreads();
  for (int k = tid; k < cnt; k += 256) {
    int2 ev = seg[k];
    int dl = ev.x >> 24;
    int slot = atomicAdd(&curs[dl], 1);
    gD[bstart + slot] = make_int2(ev.x & 0xFFFFFF, ev.y);
  }
}

// ------- P4b: per-src-bucket weighted out-degree (dw) + global max -------
__global__ void k_dw(const unsigned* __restrict__ gS, const int* __restrict__ baseAll,
                     float* __restrict__ dw, unsigned* maxbits, int NB, int N, int E) {
  __shared__ float acc[BSZ];
  int tid = threadIdx.x, b = blockIdx.x;
  int bstart = baseAll[(NB + b) * NWG] - E;
  int bend = (b + 1 < NB) ? baseAll[(NB + b + 1) * NWG] - E : E;
  if (tid < BSZ) acc[tid] = 0.f;
  __syncthreads();
  for (int k = bstart + tid; k < bend; k += 256) {
    unsigned p = gS[k];
    atomicAdd(&acc[p >> 16], __half2float(__ushort_as_half((unsigned short)(p & 0xFFFFu))));
  }
  __syncthreads();
  float m = 0.f;
  if (tid < BSZ) {
    int node = b * BSZ + tid;
    if (node < N) { dw[node] = acc[tid]; m = acc[tid]; }
  }
  for (int mm = 32; mm; mm >>= 1) m = fmaxf(m, __shfl_xor(m, mm, 64));
  if ((tid & 63) == 0) atomicMax(maxbits, __float_as_uint(m));
}

// ------- layer-1 agg: wave per node; fused relu+b1+.W2; u = dinv*(h.W2) -------
__global__ void k_agg1(const __half* __restrict__ g0, const float* __restrict__ dinv,
                       const int* __restrict__ off, const int2* __restrict__ csr,
                       const float* __restrict__ b1, const float* __restrict__ W2,
                       float* __restrict__ u, int N) {
  int lane = threadIdx.x & 63;
  int i = (blockIdx.x * blockDim.x + threadIdx.x) >> 6;
  if (i >= N) return;
  float di = dinv[i];
  float acc = di * __half2float(g0[(size_t)i * F_HID + lane]);  // self: dinv_i * h0_i
  int p0 = off[i], p1 = off[i + 1];
  for (int p = p0; p < p1; p += 64) {
    int rem = p1 - p;
    int m = rem < 64 ? rem : 64;
    int sx = 0; float wj = 0.f;
    if (lane < m) {
      int2 ed = csr[p + lane];
      sx = ed.x;
      wj = __int_as_float(ed.y) * dinv[ed.x];   // ew * dinv_s
    }
    for (int j = 0; j < m; ++j) {
      int s = __builtin_amdgcn_readlane(sx, j);
      float w = __int_as_float(__builtin_amdgcn_readlane(__float_as_int(wj), j));
      acc = fmaf(w, __half2float(g0[(size_t)s * F_HID + lane]), acc);
    }
  }
  float h = fmaxf(di * acc + b1[lane], 0.f);
  float pdt = h * W2[lane];
  for (int mm = 32; mm; mm >>= 1) pdt += __shfl_xor(pdt, mm, 64);
  if (lane == 0) u[i] = di * pdt;
}

// ------- layer-2 agg + final: z = dinv_i*(u_i + sum ew*u_s) + b2 -------
__global__ void k_agg2_final(const float* __restrict__ u, const float* __restrict__ dinv,
                             const int* __restrict__ off, const int2* __restrict__ csr,
                             const float* __restrict__ b2, const float* __restrict__ dw,
                             const unsigned* __restrict__ maxbits,
                             float* __restrict__ out, int N) {
  int lane = threadIdx.x & 63;
  int i = (blockIdx.x * blockDim.x + threadIdx.x) >> 6;
  if (i >= N) return;
  float acc = (lane == 0) ? u[i] : 0.f;
  int p0 = off[i], p1 = off[i + 1];
  for (int p = p0 + lane; p < p1; p += 64) {
    int2 ed = csr[p];
    acc = fmaf(__int_as_float(ed.y), u[ed.x], acc);
  }
  for (int mm = 32; mm; mm >>= 1) acc += __shfl_xor(acc, mm, 64);
  if (lane == 0) {
    float md = __uint_as_float(*maxbits);
    float z = dinv[i] * acc + b2[0];
    float sc = 1.0f / (1.0f + expf(-z));
    out[i] = sc * (1.0f + dw[i] / md);
  }
}

extern "C" void kernel_launch(void* const* d_in, const int* in_sizes, int n_in,
                              void* d_out, int out_size, void* d_ws, size_t ws_size,
                              hipStream_t stream) {
  const float* x  = (const float*)d_in[0];
  const int*   ei = (const int*)d_in[1];
  const float* ew = (const float*)d_in[2];
  const float* W1 = (const float*)d_in[3];
  const float* b1 = (const float*)d_in[4];
  const float* W2 = (const float*)d_in[5];
  const float* b2 = (const float*)d_in[6];
  float* out = (float*)d_out;

  int N = out_size;      // 100000
  int E = in_sizes[2];   // 3200000
  const int* src = ei;
  const int* dst = ei + E;

  int NB = (N + BSZ - 1) >> BSH;        // 782
  int TOT = 2 * NB * NWG;               // 800768
  int SB = (TOT + 1023) >> 10;          // 782 (<=1024)
  size_t shmem = (size_t)(2 * NB) * sizeof(int);

  char* w8 = (char*)d_ws;
  int2*     gD      = (int2*)w8;                         // E int2  (becomes CSR in place)
  unsigned* gS      = (unsigned*)(gD + E);               // E u32
  int*      cntAll  = (int*)(gS + E);                    // TOT i  (scanned in place)
  int*      partials= cntAll + TOT;                      // 1024 i
  int*      off     = partials + 1024;                   // N+1 i
  float*    dinv    = (float*)(off + N + 1);             // N f
  float*    dw      = dinv + N;                          // N f
  float*    u       = dw + N;                            // N f
  unsigned* maxbits = (unsigned*)(u + N);                // 1 u
  __half*   g0      = (__half*)(maxbits + 2);            // N*64 half

  k_gemm1<<<1024, 256, 0, stream>>>(x, W1, g0, N);
  k_count<<<NWG, 256, shmem, stream>>>(src, dst, cntAll, NB, E);
  k_scanA<<<SB, 1024, 0, stream>>>(cntAll, partials, TOT);
  k_scanB<<<1, 1024, 0, stream>>>(partials, SB, maxbits);
  k_scanC<<<SB, 1024, 0, stream>>>(cntAll, partials, TOT);
  k_part<<<NWG, 256, shmem, stream>>>(src, dst, ew, cntAll, gD, gS, NB, E);
  k_csr<<<NB, 256, 0, stream>>>(gD, cntAll, off, dinv, NB, N, E);
  k_dw<<<NB, 256, 0, stream>>>(gS, cntAll, dw, maxbits, NB, N, E);
  k_agg1<<<(N * 64 + 255) / 256, 256, 0, stream>>>(g0, dinv, off, gD, b1, W2, u, N);
  k_agg2_final<<<(N * 64 + 255) / 256, 256, 0, stream>>>(u, dinv, off, gD, b2, dw, maxbits, out, N);
}

// Round 5
// 482.331 us; speedup vs baseline: 2.6379x; 1.0255x over previous
//
#include <hip/hip_runtime.h>
#include <hip/hip_fp16.h>
#include <math.h>

#define F_IN 128
#define F_HID 64
#define NWG 512      // partition workgroups
#define BSH 7        // bucket shift (128 nodes per bucket)
#define BSZ 128
#define SEGCAP 6144  // max edges per bucket staged in LDS (mean 4096, ~32 sigma headroom)

// ---- fp8 e4m3 (OCP, gfx950 HW cvt) ----
__device__ __forceinline__ unsigned char f32_to_fp8(float v) {
  unsigned r = __builtin_amdgcn_cvt_pk_fp8_f32(v, v, 0, false);
  return (unsigned char)(r & 0xFFu);
}
__device__ __forceinline__ float fp8_to_f32(unsigned char b) {
  return __builtin_amdgcn_cvt_f32_fp8((unsigned)b, 0);
}

// ------- P1: per-(bucket, wg) counts for dst-buckets and src-buckets (LDS only) -------
__global__ void k_count(const int* __restrict__ src, const int* __restrict__ dst,
                        int* __restrict__ cntAll, int NB, int E) {
  extern __shared__ int sh[];
  int* hD = sh;         // NB
  int* hS = sh + NB;    // NB
  int tid = threadIdx.x, w = blockIdx.x;
  for (int k = tid; k < 2 * NB; k += 256) sh[k] = 0;
  __syncthreads();
  int C = (E + NWG - 1) / NWG;
  int e0 = w * C, e1 = min(E, e0 + C);
  for (int e = e0 + tid; e < e1; e += 256) {
    atomicAdd(&hD[dst[e] >> BSH], 1);
    atomicAdd(&hS[src[e] >> BSH], 1);
  }
  __syncthreads();
  for (int b = tid; b < NB; b += 256) {
    cntAll[b * NWG + w] = hD[b];
    cntAll[(NB + b) * NWG + w] = hS[b];
  }
}

// ---------------- flat exclusive scan (in place), 1024-thread blocks ----------------
__global__ void k_scanA(int* __restrict__ data, int* __restrict__ partials, int TOT) {
  __shared__ int lds[1024];
  int tid = threadIdx.x;
  int g = blockIdx.x * 1024 + tid;
  int v = (g < TOT) ? data[g] : 0;
  lds[tid] = v; __syncthreads();
  for (int o = 1; o < 1024; o <<= 1) {
    int t = (tid >= o) ? lds[tid - o] : 0;
    __syncthreads();
    lds[tid] += t;
    __syncthreads();
  }
  if (g < TOT) data[g] = lds[tid] - v;
  if (tid == 1023) partials[blockIdx.x] = lds[1023];
}

__global__ void k_scanB(int* partials, int nb, unsigned* maxbits) {
  __shared__ int lds[1024];
  int tid = threadIdx.x;
  if (tid == 0) *maxbits = 0u;
  int v = (tid < nb) ? partials[tid] : 0;
  lds[tid] = v; __syncthreads();
  for (int o = 1; o < 1024; o <<= 1) {
    int t = (tid >= o) ? lds[tid - o] : 0;
    __syncthreads();
    lds[tid] += t;
    __syncthreads();
  }
  if (tid < nb) partials[tid] = lds[tid] - v;
}

__global__ void k_scanC(int* __restrict__ data, const int* __restrict__ partials, int TOT) {
  int g = blockIdx.x * 1024 + threadIdx.x;
  if (g < TOT) data[g] += partials[g >> 10];
}

// ------- P3: partition edges into dst-buckets (int2) and src-buckets (packed u32) -------
__global__ void k_part(const int* __restrict__ src, const int* __restrict__ dst,
                       const float* __restrict__ ew, const int* __restrict__ baseAll,
                       int2* __restrict__ gD, unsigned* __restrict__ gS, int NB, int E) {
  extern __shared__ int sh[];
  int* cD = sh;
  int* cS = sh + NB;
  int tid = threadIdx.x, w = blockIdx.x;
  for (int b = tid; b < NB; b += 256) {
    cD[b] = baseAll[b * NWG + w];
    cS[b] = baseAll[(NB + b) * NWG + w] - E;
  }
  __syncthreads();
  int C = (E + NWG - 1) / NWG;
  int e0 = w * C, e1 = min(E, e0 + C);
  for (int e = e0 + tid; e < e1; e += 256) {
    int s = src[e], d = dst[e];
    float wv = ew[e];
    int pD = atomicAdd(&cD[d >> BSH], 1);
    gD[pD] = make_int2(s | ((d & (BSZ - 1)) << 24), __float_as_int(wv));
    int pS = atomicAdd(&cS[s >> BSH], 1);
    unsigned hb = (unsigned)__half_as_ushort(__float2half(wv));
    gS[pS] = ((unsigned)(s & (BSZ - 1)) << 16) | hb;
  }
}

// ------- P4a: per-dst-bucket local counting sort -> CSR (in place) + off + dinv -------
__global__ void k_csr(int2* __restrict__ gD, const int* __restrict__ baseAll,
                      int* __restrict__ off, float* __restrict__ dinv,
                      int NB, int N, int E) {
  __shared__ int2 seg[SEGCAP];
  __shared__ int hist[BSZ];
  __shared__ int curs[BSZ];
  __shared__ float degf[BSZ];
  int tid = threadIdx.x, b = blockIdx.x;
  int bstart = baseAll[b * NWG];
  int bend = (b + 1 < NB) ? baseAll[(b + 1) * NWG] : E;
  int cnt = bend - bstart;
  for (int k = tid; k < cnt; k += 256) seg[k] = gD[bstart + k];
  if (tid < BSZ) { hist[tid] = 0; degf[tid] = 0.f; }
  __syncthreads();
  for (int k = tid; k < cnt; k += 256) {
    int dl = seg[k].x >> 24;
    atomicAdd(&hist[dl], 1);
    atomicAdd(&degf[dl], __int_as_float(seg[k].y));
  }
  __syncthreads();
  int v = (tid < BSZ) ? hist[tid] : 0;
  for (int o = 1; o < BSZ; o <<= 1) {
    int t = (tid < BSZ && tid >= o) ? hist[tid - o] : 0;
    __syncthreads();
    if (tid < BSZ) hist[tid] += t;
    __syncthreads();
  }
  if (tid < BSZ) {
    int excl = hist[tid] - v;
    curs[tid] = excl;
    int node = b * BSZ + tid;
    if (node < N) {
      off[node] = bstart + excl;
      dinv[node] = rsqrtf(1.0f + degf[tid]);
    }
  }
  if (b == NB - 1 && tid == 0) off[N] = E;
  __syncthreads();
  for (int k = tid; k < cnt; k += 256) {
    int2 ev = seg[k];
    int dl = ev.x >> 24;
    int slot = atomicAdd(&curs[dl], 1);
    gD[bstart + slot] = make_int2(ev.x & 0xFFFFFF, ev.y);
  }
}

// ------- P4b: per-src-bucket weighted out-degree (dw) + global max -------
__global__ void k_dw(const unsigned* __restrict__ gS, const int* __restrict__ baseAll,
                     float* __restrict__ dw, unsigned* maxbits, int NB, int N, int E) {
  __shared__ float acc[BSZ];
  int tid = threadIdx.x, b = blockIdx.x;
  int bstart = baseAll[(NB + b) * NWG] - E;
  int bend = (b + 1 < NB) ? baseAll[(NB + b + 1) * NWG] - E : E;
  if (tid < BSZ) acc[tid] = 0.f;
  __syncthreads();
  for (int k = bstart + tid; k < bend; k += 256) {
    unsigned p = gS[k];
    atomicAdd(&acc[p >> 16], __half2float(__ushort_as_half((unsigned short)(p & 0xFFFFu))));
  }
  __syncthreads();
  float m = 0.f;
  if (tid < BSZ) {
    int node = b * BSZ + tid;
    if (node < N) { dw[node] = acc[tid]; m = acc[tid]; }
  }
  for (int mm = 32; mm; mm >>= 1) m = fmaxf(m, __shfl_xor(m, mm, 64));
  if ((tid & 63) == 0) atomicMax(maxbits, __float_as_uint(m));
}

// ------- g0 = dinv[i] * (x @ W1) row, stored fp8 e4m3 (wave per row) -------
__global__ void k_gemm1(const float* __restrict__ x, const float* __restrict__ W1,
                        const float* __restrict__ dinv, unsigned char* __restrict__ g0, int N) {
  int lane = threadIdx.x & 63;
  int wid = (blockIdx.x * blockDim.x + threadIdx.x) >> 6;
  int nw = (gridDim.x * blockDim.x) >> 6;
  float w[F_IN];
#pragma unroll
  for (int k = 0; k < F_IN; ++k) w[k] = W1[k * F_HID + lane];
  for (int i = wid; i < N; i += nw) {
    float xa = x[(size_t)i * F_IN + lane];
    float xb = x[(size_t)i * F_IN + 64 + lane];
    float acc0 = 0.f, acc1 = 0.f;
#pragma unroll
    for (int k = 0; k < 64; ++k) {
      float xk0 = __int_as_float(__builtin_amdgcn_readlane(__float_as_int(xa), k));
      float xk1 = __int_as_float(__builtin_amdgcn_readlane(__float_as_int(xb), k));
      acc0 = fmaf(xk0, w[k], acc0);
      acc1 = fmaf(xk1, w[64 + k], acc1);
    }
    g0[(size_t)i * F_HID + lane] = f32_to_fp8((acc0 + acc1) * dinv[i]);
  }
}

// ------- layer-1 agg: wave per node; g0 pre-scaled by dinv_s; fused relu+b1+.W2 -------
__global__ void k_agg1(const unsigned char* __restrict__ g0, const float* __restrict__ dinv,
                       const int* __restrict__ off, const int2* __restrict__ csr,
                       const float* __restrict__ b1, const float* __restrict__ W2,
                       float* __restrict__ u, int N) {
  int lane = threadIdx.x & 63;
  int i = (blockIdx.x * blockDim.x + threadIdx.x) >> 6;
  if (i >= N) return;
  float acc = fp8_to_f32(g0[(size_t)i * F_HID + lane]);  // self: dinv_i * h0_i
  int p0 = off[i], p1 = off[i + 1];
  for (int p = p0; p < p1; p += 64) {
    int rem = p1 - p;
    int m = rem < 64 ? rem : 64;
    int2 ed = make_int2(0, 0);
    if (lane < m) ed = csr[p + lane];
    for (int j = 0; j < m; ++j) {
      int s = __builtin_amdgcn_readlane(ed.x, j);
      float w = __int_as_float(__builtin_amdgcn_readlane(ed.y, j));
      acc = fmaf(w, fp8_to_f32(g0[(size_t)s * F_HID + lane]), acc);
    }
  }
  float di = dinv[i];
  float h = fmaxf(di * acc + b1[lane], 0.f);
  float pdt = h * W2[lane];
  for (int mm = 32; mm; mm >>= 1) pdt += __shfl_xor(pdt, mm, 64);
  if (lane == 0) u[i] = di * pdt;
}

// ------- layer-2 agg + final: 2 nodes per wave (32-lane groups) -------
__global__ void k_agg2_final(const float* __restrict__ u, const float* __restrict__ dinv,
                             const int* __restrict__ off, const int2* __restrict__ csr,
                             const float* __restrict__ b2, const float* __restrict__ dw,
                             const unsigned* __restrict__ maxbits,
                             float* __restrict__ out, int N) {
  int lane32 = threadIdx.x & 31;
  int i = blockIdx.x * 8 + (threadIdx.x >> 5);   // 8 nodes per 256-thread block
  if (i >= N) return;
  float acc = (lane32 == 0) ? u[i] : 0.f;        // self (u_i)
  int p0 = off[i], p1 = off[i + 1];
  for (int p = p0 + lane32; p < p1; p += 32) {
    int2 ed = csr[p];
    acc = fmaf(__int_as_float(ed.y), u[ed.x], acc);
  }
  for (int mm = 16; mm; mm >>= 1) acc += __shfl_xor(acc, mm, 64);
  if (lane32 == 0) {
    float md = __uint_as_float(*maxbits);
    float z = dinv[i] * acc + b2[0];
    float sc = 1.0f / (1.0f + expf(-z));
    out[i] = sc * (1.0f + dw[i] / md);
  }
}

extern "C" void kernel_launch(void* const* d_in, const int* in_sizes, int n_in,
                              void* d_out, int out_size, void* d_ws, size_t ws_size,
                              hipStream_t stream) {
  const float* x  = (const float*)d_in[0];
  const int*   ei = (const int*)d_in[1];
  const float* ew = (const float*)d_in[2];
  const float* W1 = (const float*)d_in[3];
  const float* b1 = (const float*)d_in[4];
  const float* W2 = (const float*)d_in[5];
  const float* b2 = (const float*)d_in[6];
  float* out = (float*)d_out;

  int N = out_size;      // 100000
  int E = in_sizes[2];   // 3200000
  const int* src = ei;
  const int* dst = ei + E;

  int NB = (N + BSZ - 1) >> BSH;        // 782
  int TOT = 2 * NB * NWG;               // 800768
  int SB = (TOT + 1023) >> 10;          // 782 (<=1024)
  size_t shmem = (size_t)(2 * NB) * sizeof(int);

  char* w8 = (char*)d_ws;
  int2*     gD      = (int2*)w8;                         // E int2  (becomes CSR in place)
  unsigned* gS      = (unsigned*)(gD + E);               // E u32
  int*      cntAll  = (int*)(gS + E);                    // TOT i  (scanned in place)
  int*      partials= cntAll + TOT;                      // 1024 i
  int*      off     = partials + 1024;                   // N+1 i
  float*    dinv    = (float*)(off + N + 1);             // N f
  float*    dw      = dinv + N;                          // N f
  float*    u       = dw + N;                            // N f
  unsigned* maxbits = (unsigned*)(u + N);                // 1 u
  unsigned char* g0 = (unsigned char*)(maxbits + 2);     // N*64 fp8

  k_count<<<NWG, 256, shmem, stream>>>(src, dst, cntAll, NB, E);
  k_scanA<<<SB, 1024, 0, stream>>>(cntAll, partials, TOT);
  k_scanB<<<1, 1024, 0, stream>>>(partials, SB, maxbits);
  k_scanC<<<SB, 1024, 0, stream>>>(cntAll, partials, TOT);
  k_part<<<NWG, 256, shmem, stream>>>(src, dst, ew, cntAll, gD, gS, NB, E);
  k_csr<<<NB, 256, 0, stream>>>(gD, cntAll, off, dinv, NB, N, E);
  k_dw<<<NB, 256, 0, stream>>>(gS, cntAll, dw, maxbits, NB, N, E);
  k_gemm1<<<1024, 256, 0, stream>>>(x, W1, dinv, g0, N);
  k_agg1<<<(N * 64 + 255) / 256, 256, 0, stream>>>(g0, dinv, off, gD, b1, W2, u, N);
  k_agg2_final<<<(N + 7) / 8, 256, 0, stream>>>(u, dinv, off, gD, b2, dw, maxbits, out, N);
}

// Round 7
// 379.436 us; speedup vs baseline: 3.3532x; 1.2712x over previous
//
#include <hip/hip_runtime.h>
#include <hip/hip_fp16.h>
#include <math.h>

#define F_IN 128
#define F_HID 64
#define NWG 512      // partition workgroups
#define BSH 7        // bucket shift (128 nodes per bucket)
#define BSZ 128
#define SEGCAP 6144  // max edges per bucket staged in LDS (mean 4096, ~32 sigma headroom)

typedef float f32x2 __attribute__((ext_vector_type(2)));

// ---- fp8 e4m3 (OCP, gfx950 HW cvt) ----
__device__ __forceinline__ unsigned char f32_to_fp8(float v) {
  unsigned r = __builtin_amdgcn_cvt_pk_fp8_f32(v, v, 0, false);
  return (unsigned char)(r & 0xFFu);
}

// ------- P1: per-(bucket, wg) counts for dst-buckets and src-buckets (LDS only) -------
__global__ void k_count(const int* __restrict__ src, const int* __restrict__ dst,
                        int* __restrict__ cntAll, int NB, int E) {
  extern __shared__ int sh[];
  int* hD = sh;         // NB
  int* hS = sh + NB;    // NB
  int tid = threadIdx.x, w = blockIdx.x;
  for (int k = tid; k < 2 * NB; k += 256) sh[k] = 0;
  __syncthreads();
  int C = (E + NWG - 1) / NWG;
  int e0 = w * C, e1 = min(E, e0 + C);
  for (int e = e0 + tid; e < e1; e += 256) {
    atomicAdd(&hD[dst[e] >> BSH], 1);
    atomicAdd(&hS[src[e] >> BSH], 1);
  }
  __syncthreads();
  for (int b = tid; b < NB; b += 256) {
    cntAll[b * NWG + w] = hD[b];
    cntAll[(NB + b) * NWG + w] = hS[b];
  }
}

// ---------------- flat exclusive scan (in place), 1024-thread blocks ----------------
__global__ void k_scanA(int* __restrict__ data, int* __restrict__ partials, int TOT) {
  __shared__ int lds[1024];
  int tid = threadIdx.x;
  int g = blockIdx.x * 1024 + tid;
  int v = (g < TOT) ? data[g] : 0;
  lds[tid] = v; __syncthreads();
  for (int o = 1; o < 1024; o <<= 1) {
    int t = (tid >= o) ? lds[tid - o] : 0;
    __syncthreads();
    lds[tid] += t;
    __syncthreads();
  }
  if (g < TOT) data[g] = lds[tid] - v;
  if (tid == 1023) partials[blockIdx.x] = lds[1023];
}

__global__ void k_scanB(int* partials, int nb, unsigned* maxbits) {
  __shared__ int lds[1024];
  int tid = threadIdx.x;
  if (tid == 0) *maxbits = 0u;
  int v = (tid < nb) ? partials[tid] : 0;
  lds[tid] = v; __syncthreads();
  for (int o = 1; o < 1024; o <<= 1) {
    int t = (tid >= o) ? lds[tid - o] : 0;
    __syncthreads();
    lds[tid] += t;
    __syncthreads();
  }
  if (tid < nb) partials[tid] = lds[tid] - v;
}

__global__ void k_scanC(int* __restrict__ data, const int* __restrict__ partials, int TOT) {
  int g = blockIdx.x * 1024 + threadIdx.x;
  if (g < TOT) data[g] += partials[g >> 10];
}

// ------- P3: partition edges into dst-buckets (int2) and src-buckets (packed u32) -------
__global__ void k_part(const int* __restrict__ src, const int* __restrict__ dst,
                       const float* __restrict__ ew, const int* __restrict__ baseAll,
                       int2* __restrict__ gD, unsigned* __restrict__ gS, int NB, int E) {
  extern __shared__ int sh[];
  int* cD = sh;
  int* cS = sh + NB;
  int tid = threadIdx.x, w = blockIdx.x;
  for (int b = tid; b < NB; b += 256) {
    cD[b] = baseAll[b * NWG + w];
    cS[b] = baseAll[(NB + b) * NWG + w] - E;
  }
  __syncthreads();
  int C = (E + NWG - 1) / NWG;
  int e0 = w * C, e1 = min(E, e0 + C);
  for (int e = e0 + tid; e < e1; e += 256) {
    int s = src[e], d = dst[e];
    float wv = ew[e];
    int pD = atomicAdd(&cD[d >> BSH], 1);
    gD[pD] = make_int2(s | ((d & (BSZ - 1)) << 24), __float_as_int(wv));
    int pS = atomicAdd(&cS[s >> BSH], 1);
    unsigned hb = (unsigned)__half_as_ushort(__float2half(wv));
    gS[pS] = ((unsigned)(s & (BSZ - 1)) << 16) | hb;
  }
}

// ------- P4a: per-dst-bucket local counting sort -> CSR (in place) + off + dinv -------
__global__ void k_csr(int2* __restrict__ gD, const int* __restrict__ baseAll,
                      int* __restrict__ off, float* __restrict__ dinv,
                      int NB, int N, int E) {
  __shared__ int2 seg[SEGCAP];
  __shared__ int hist[BSZ];
  __shared__ int curs[BSZ];
  __shared__ float degf[BSZ];
  int tid = threadIdx.x, b = blockIdx.x;
  int bstart = baseAll[b * NWG];
  int bend = (b + 1 < NB) ? baseAll[(b + 1) * NWG] : E;
  int cnt = bend - bstart;
  for (int k = tid; k < cnt; k += 256) seg[k] = gD[bstart + k];
  if (tid < BSZ) { hist[tid] = 0; degf[tid] = 0.f; }
  __syncthreads();
  for (int k = tid; k < cnt; k += 256) {
    int dl = seg[k].x >> 24;
    atomicAdd(&hist[dl], 1);
    atomicAdd(&degf[dl], __int_as_float(seg[k].y));
  }
  __syncthreads();
  int v = (tid < BSZ) ? hist[tid] : 0;
  for (int o = 1; o < BSZ; o <<= 1) {
    int t = (tid < BSZ && tid >= o) ? hist[tid - o] : 0;
    __syncthreads();
    if (tid < BSZ) hist[tid] += t;
    __syncthreads();
  }
  if (tid < BSZ) {
    int excl = hist[tid] - v;
    curs[tid] = excl;
    int node = b * BSZ + tid;
    if (node < N) {
      off[node] = bstart + excl;
      dinv[node] = rsqrtf(1.0f + degf[tid]);
    }
  }
  if (b == NB - 1 && tid == 0) off[N] = E;
  __syncthreads();
  for (int k = tid; k < cnt; k += 256) {
    int2 ev = seg[k];
    int dl = ev.x >> 24;
    int slot = atomicAdd(&curs[dl], 1);
    gD[bstart + slot] = make_int2(ev.x & 0xFFFFFF, ev.y);
  }
}

// ------- P4b: per-src-bucket weighted out-degree (dw) + global max -------
__global__ void k_dw(const unsigned* __restrict__ gS, const int* __restrict__ baseAll,
                     float* __restrict__ dw, unsigned* maxbits, int NB, int N, int E) {
  __shared__ float acc[BSZ];
  int tid = threadIdx.x, b = blockIdx.x;
  int bstart = baseAll[(NB + b) * NWG] - E;
  int bend = (b + 1 < NB) ? baseAll[(NB + b + 1) * NWG] - E : E;
  if (tid < BSZ) acc[tid] = 0.f;
  __syncthreads();
  for (int k = bstart + tid; k < bend; k += 256) {
    unsigned p = gS[k];
    atomicAdd(&acc[p >> 16], __half2float(__ushort_as_half((unsigned short)(p & 0xFFFFu))));
  }
  __syncthreads();
  float m = 0.f;
  if (tid < BSZ) {
    int node = b * BSZ + tid;
    if (node < N) { dw[node] = acc[tid]; m = acc[tid]; }
  }
  for (int mm = 32; mm; mm >>= 1) m = fmaxf(m, __shfl_xor(m, mm, 64));
  if ((tid & 63) == 0) atomicMax(maxbits, __float_as_uint(m));
}

// ------- g0 = dinv[i] * (x @ W1) row, stored fp8 e4m3 (wave per row) -------
__global__ void k_gemm1(const float* __restrict__ x, const float* __restrict__ W1,
                        const float* __restrict__ dinv, unsigned char* __restrict__ g0, int N) {
  int lane = threadIdx.x & 63;
  int wid = (blockIdx.x * blockDim.x + threadIdx.x) >> 6;
  int nw = (gridDim.x * blockDim.x) >> 6;
  float w[F_IN];
#pragma unroll
  for (int k = 0; k < F_IN; ++k) w[k] = W1[k * F_HID + lane];
  for (int i = wid; i < N; i += nw) {
    float xa = x[(size_t)i * F_IN + lane];
    float xb = x[(size_t)i * F_IN + 64 + lane];
    float acc0 = 0.f, acc1 = 0.f;
#pragma unroll
    for (int k = 0; k < 64; ++k) {
      float xk0 = __int_as_float(__builtin_amdgcn_readlane(__float_as_int(xa), k));
      float xk1 = __int_as_float(__builtin_amdgcn_readlane(__float_as_int(xb), k));
      acc0 = fmaf(xk0, w[k], acc0);
      acc1 = fmaf(xk1, w[64 + k], acc1);
    }
    g0[(size_t)i * F_HID + lane] = f32_to_fp8((acc0 + acc1) * dinv[i]);
  }
}

// ------- layer-1 agg: wave per node; 8 edge-slots x 8 lanes x 8 features -------
__global__ void k_agg1(const unsigned char* __restrict__ g0, const float* __restrict__ dinv,
                       const int* __restrict__ off, const int2* __restrict__ csr,
                       const float* __restrict__ b1, const float* __restrict__ W2,
                       float* __restrict__ u, int N) {
  int lane = threadIdx.x & 63;
  int grp = lane >> 3;        // edge slot 0..7
  int l8  = lane & 7;         // feature octet 0..7 (features 8*l8 .. 8*l8+7)
  int i = (blockIdx.x * blockDim.x + threadIdx.x) >> 6;
  if (i >= N) return;
  const uint2* g0v = (const uint2*)g0;
  float acc[8] = {0.f, 0.f, 0.f, 0.f, 0.f, 0.f, 0.f, 0.f};
  if (grp == 0) {             // self contribution once (group 0)
    uint2 rv = g0v[(size_t)i * 8 + l8];
    f32x2 c0 = __builtin_amdgcn_cvt_pk_f32_fp8(rv.x, false);
    f32x2 c1 = __builtin_amdgcn_cvt_pk_f32_fp8(rv.x, true);
    f32x2 c2 = __builtin_amdgcn_cvt_pk_f32_fp8(rv.y, false);
    f32x2 c3 = __builtin_amdgcn_cvt_pk_f32_fp8(rv.y, true);
    acc[0] += c0.x; acc[1] += c0.y; acc[2] += c1.x; acc[3] += c1.y;
    acc[4] += c2.x; acc[5] += c2.y; acc[6] += c3.x; acc[7] += c3.y;
  }
  int p0 = off[i], p1 = off[i + 1];
  for (int p = p0; p < p1; p += 64) {
    int m = min(p1 - p, 64);
    int2 ed = make_int2(0, 0);
    if (lane < m) ed = csr[p + lane];
#pragma unroll
    for (int jj = 0; jj < 8; ++jj) {
      int j = jj * 8 + grp;                       // this slot's edge index in batch
      int s = __shfl(ed.x, j, 64);
      float w = __int_as_float(__shfl(ed.y, j, 64));
      if (j < m) {
        uint2 rv = g0v[(size_t)s * 8 + l8];
        f32x2 c0 = __builtin_amdgcn_cvt_pk_f32_fp8(rv.x, false);
        f32x2 c1 = __builtin_amdgcn_cvt_pk_f32_fp8(rv.x, true);
        f32x2 c2 = __builtin_amdgcn_cvt_pk_f32_fp8(rv.y, false);
        f32x2 c3 = __builtin_amdgcn_cvt_pk_f32_fp8(rv.y, true);
        acc[0] = fmaf(w, c0.x, acc[0]); acc[1] = fmaf(w, c0.y, acc[1]);
        acc[2] = fmaf(w, c1.x, acc[2]); acc[3] = fmaf(w, c1.y, acc[3]);
        acc[4] = fmaf(w, c2.x, acc[4]); acc[5] = fmaf(w, c2.y, acc[5]);
        acc[6] = fmaf(w, c3.x, acc[6]); acc[7] = fmaf(w, c3.y, acc[7]);
      }
    }
  }
  // fold the 8 edge slots (lane bits 3..5)
#pragma unroll
  for (int k = 0; k < 8; ++k) {
    acc[k] += __shfl_xor(acc[k], 8, 64);
    acc[k] += __shfl_xor(acc[k], 16, 64);
    acc[k] += __shfl_xor(acc[k], 32, 64);
  }
  float di = dinv[i];
  float pdt = 0.f;
#pragma unroll
  for (int k = 0; k < 8; ++k) {
    int f = l8 * 8 + k;
    float h = fmaxf(di * acc[k] + b1[f], 0.f);
    pdt = fmaf(h, W2[f], pdt);
  }
  pdt += __shfl_xor(pdt, 1, 64);
  pdt += __shfl_xor(pdt, 2, 64);
  pdt += __shfl_xor(pdt, 4, 64);
  if (lane == 0) u[i] = di * pdt;
}

// ------- layer-2 agg + final: 2 nodes per wave (32-lane groups) -------
__global__ void k_agg2_final(const float* __restrict__ u, const float* __restrict__ dinv,
                             const int* __restrict__ off, const int2* __restrict__ csr,
                             const float* __restrict__ b2, const float* __restrict__ dw,
                             const unsigned* __restrict__ maxbits,
                             float* __restrict__ out, int N) {
  int lane32 = threadIdx.x & 31;
  int i = blockIdx.x * 8 + (threadIdx.x >> 5);   // 8 nodes per 256-thread block
  if (i >= N) return;
  float acc = (lane32 == 0) ? u[i] : 0.f;        // self (u_i)
  int p0 = off[i], p1 = off[i + 1];
  for (int p = p0 + lane32; p < p1; p += 32) {
    int2 ed = csr[p];
    acc = fmaf(__int_as_float(ed.y), u[ed.x], acc);
  }
  for (int mm = 16; mm; mm >>= 1) acc += __shfl_xor(acc, mm, 64);
  if (lane32 == 0) {
    float md = __uint_as_float(*maxbits);
    float z = dinv[i] * acc + b2[0];
    float sc = 1.0f / (1.0f + expf(-z));
    out[i] = sc * (1.0f + dw[i] / md);
  }
}

extern "C" void kernel_launch(void* const* d_in, const int* in_sizes, int n_in,
                              void* d_out, int out_size, void* d_ws, size_t ws_size,
                              hipStream_t stream) {
  const float* x  = (const float*)d_in[0];
  const int*   ei = (const int*)d_in[1];
  const float* ew = (const float*)d_in[2];
  const float* W1 = (const float*)d_in[3];
  const float* b1 = (const float*)d_in[4];
  const float* W2 = (const float*)d_in[5];
  const float* b2 = (const float*)d_in[6];
  float* out = (float*)d_out;

  int N = out_size;      // 100000
  int E = in_sizes[2];   // 3200000
  const int* src = ei;
  const int* dst = ei + E;

  int NB = (N + BSZ - 1) >> BSH;        // 782
  int TOT = 2 * NB * NWG;               // 800768
  int SB = (TOT + 1023) >> 10;          // 782 (<=1024)
  size_t shmem = (size_t)(2 * NB) * sizeof(int);

  char* w8 = (char*)d_ws;
  int2*     gD      = (int2*)w8;                         // E int2  (becomes CSR in place)
  unsigned* gS      = (unsigned*)(gD + E);               // E u32
  int*      cntAll  = (int*)(gS + E);                    // TOT i  (scanned in place)
  int*      partials= cntAll + TOT;                      // 1024 i
  int*      off     = partials + 1024;                   // N+1 i
  float*    dinv    = (float*)(off + N + 1);             // N f
  float*    dw      = dinv + N;                          // N f
  float*    u       = dw + N;                            // N f
  unsigned* maxbits = (unsigned*)(u + N);                // 1 u
  unsigned char* g0 = (unsigned char*)(maxbits + 2);     // N*64 fp8

  k_count<<<NWG, 256, shmem, stream>>>(src, dst, cntAll, NB, E);
  k_scanA<<<SB, 1024, 0, stream>>>(cntAll, partials, TOT);
  k_scanB<<<1, 1024, 0, stream>>>(partials, SB, maxbits);
  k_scanC<<<SB, 1024, 0, stream>>>(cntAll, partials, TOT);
  k_part<<<NWG, 256, shmem, stream>>>(src, dst, ew, cntAll, gD, gS, NB, E);
  k_csr<<<NB, 256, 0, stream>>>(gD, cntAll, off, dinv, NB, N, E);
  k_dw<<<NB, 256, 0, stream>>>(gS, cntAll, dw, maxbits, NB, N, E);
  k_gemm1<<<1024, 256, 0, stream>>>(x, W1, dinv, g0, N);
  k_agg1<<<(N * 64 + 255) / 256, 256, 0, stream>>>(g0, dinv, off, gD, b1, W2, u, N);
  k_agg2_final<<<(N + 7) / 8, 256, 0, stream>>>(u, dinv, off, gD, b2, dw, maxbits, out, N);
}

// Round 8
// 370.222 us; speedup vs baseline: 3.4367x; 1.0249x over previous
//
#include <hip/hip_runtime.h>
#include <hip/hip_fp16.h>
#include <math.h>

#define F_IN 128
#define F_HID 64
#define NWG 512      // partition chunks (= blocks of k_count/k_part)
#define PT 1024      // threads per partition block (16 waves -> full occupancy)
#define BSH 7        // bucket shift (128 nodes per bucket)
#define BSZ 128
#define SEGCAP 6144  // max edges per bucket staged in LDS (mean 4096, ~32 sigma headroom)

typedef float f32x2 __attribute__((ext_vector_type(2)));

// ---- fp8 e4m3 (OCP, gfx950 HW cvt) ----
__device__ __forceinline__ unsigned char f32_to_fp8(float v) {
  unsigned r = __builtin_amdgcn_cvt_pk_fp8_f32(v, v, 0, false);
  return (unsigned char)(r & 0xFFu);
}

// ------- P1: per-(bucket, wg) counts for dst-buckets and src-buckets (LDS only) -------
__global__ void k_count(const int* __restrict__ src, const int* __restrict__ dst,
                        int* __restrict__ cntAll, int NB, int E) {
  extern __shared__ int sh[];
  int* hD = sh;         // NB
  int* hS = sh + NB;    // NB
  int tid = threadIdx.x, w = blockIdx.x;
  for (int k = tid; k < 2 * NB; k += PT) sh[k] = 0;
  __syncthreads();
  int C = (E + NWG - 1) / NWG;
  int e0 = w * C, e1 = min(E, e0 + C);
  for (int e = e0 + tid; e < e1; e += PT) {
    atomicAdd(&hD[dst[e] >> BSH], 1);
    atomicAdd(&hS[src[e] >> BSH], 1);
  }
  __syncthreads();
  for (int b = tid; b < NB; b += PT) {
    cntAll[b * NWG + w] = hD[b];
    cntAll[(NB + b) * NWG + w] = hS[b];
  }
}

// ---------------- flat exclusive scan (in place), 1024-thread blocks ----------------
__global__ void k_scanA(int* __restrict__ data, int* __restrict__ partials, int TOT) {
  __shared__ int lds[1024];
  int tid = threadIdx.x;
  int g = blockIdx.x * 1024 + tid;
  int v = (g < TOT) ? data[g] : 0;
  lds[tid] = v; __syncthreads();
  for (int o = 1; o < 1024; o <<= 1) {
    int t = (tid >= o) ? lds[tid - o] : 0;
    __syncthreads();
    lds[tid] += t;
    __syncthreads();
  }
  if (g < TOT) data[g] = lds[tid] - v;
  if (tid == 1023) partials[blockIdx.x] = lds[1023];
}

__global__ void k_scanB(int* partials, int nb, unsigned* maxbits) {
  __shared__ int lds[1024];
  int tid = threadIdx.x;
  if (tid == 0) *maxbits = 0u;
  int v = (tid < nb) ? partials[tid] : 0;
  lds[tid] = v; __syncthreads();
  for (int o = 1; o < 1024; o <<= 1) {
    int t = (tid >= o) ? lds[tid - o] : 0;
    __syncthreads();
    lds[tid] += t;
    __syncthreads();
  }
  if (tid < nb) partials[tid] = lds[tid] - v;
}

__global__ void k_scanC(int* __restrict__ data, const int* __restrict__ partials, int TOT) {
  int g = blockIdx.x * 1024 + threadIdx.x;
  if (g < TOT) data[g] += partials[g >> 10];
}

// ------- P3: partition edges into dst-buckets (int2) and src-buckets (packed u32) -------
__global__ void k_part(const int* __restrict__ src, const int* __restrict__ dst,
                       const float* __restrict__ ew, const int* __restrict__ baseAll,
                       int2* __restrict__ gD, unsigned* __restrict__ gS, int NB, int E) {
  extern __shared__ int sh[];
  int* cD = sh;
  int* cS = sh + NB;
  int tid = threadIdx.x, w = blockIdx.x;
  for (int b = tid; b < NB; b += PT) {
    cD[b] = baseAll[b * NWG + w];
    cS[b] = baseAll[(NB + b) * NWG + w] - E;
  }
  __syncthreads();
  int C = (E + NWG - 1) / NWG;
  int e0 = w * C, e1 = min(E, e0 + C);
  for (int e = e0 + tid; e < e1; e += PT) {
    int s = src[e], d = dst[e];
    float wv = ew[e];
    int pD = atomicAdd(&cD[d >> BSH], 1);
    gD[pD] = make_int2(s | ((d & (BSZ - 1)) << 24), __float_as_int(wv));
    int pS = atomicAdd(&cS[s >> BSH], 1);
    unsigned hb = (unsigned)__half_as_ushort(__float2half(wv));
    gS[pS] = ((unsigned)(s & (BSZ - 1)) << 16) | hb;
  }
}

// ------- P4a: per-dst-bucket local counting sort -> CSR (in place) + off + dinv -------
__global__ void k_csr(int2* __restrict__ gD, const int* __restrict__ baseAll,
                      int* __restrict__ off, float* __restrict__ dinv,
                      int NB, int N, int E) {
  __shared__ int2 seg[SEGCAP];
  __shared__ int hist[BSZ];
  __shared__ int curs[BSZ];
  __shared__ float degf[BSZ];
  int tid = threadIdx.x, b = blockIdx.x;
  int bstart = baseAll[b * NWG];
  int bend = (b + 1 < NB) ? baseAll[(b + 1) * NWG] : E;
  int cnt = bend - bstart;
  for (int k = tid; k < cnt; k += 256) seg[k] = gD[bstart + k];
  if (tid < BSZ) { hist[tid] = 0; degf[tid] = 0.f; }
  __syncthreads();
  for (int k = tid; k < cnt; k += 256) {
    int dl = seg[k].x >> 24;
    atomicAdd(&hist[dl], 1);
    atomicAdd(&degf[dl], __int_as_float(seg[k].y));
  }
  __syncthreads();
  int v = (tid < BSZ) ? hist[tid] : 0;
  for (int o = 1; o < BSZ; o <<= 1) {
    int t = (tid < BSZ && tid >= o) ? hist[tid - o] : 0;
    __syncthreads();
    if (tid < BSZ) hist[tid] += t;
    __syncthreads();
  }
  if (tid < BSZ) {
    int excl = hist[tid] - v;
    curs[tid] = excl;
    int node = b * BSZ + tid;
    if (node < N) {
      off[node] = bstart + excl;
      dinv[node] = rsqrtf(1.0f + degf[tid]);
    }
  }
  if (b == NB - 1 && tid == 0) off[N] = E;
  __syncthreads();
  for (int k = tid; k < cnt; k += 256) {
    int2 ev = seg[k];
    int dl = ev.x >> 24;
    int slot = atomicAdd(&curs[dl], 1);
    gD[bstart + slot] = make_int2(ev.x & 0xFFFFFF, ev.y);
  }
}

// ------- P4b: per-src-bucket weighted out-degree (dw) + global max -------
__global__ void k_dw(const unsigned* __restrict__ gS, const int* __restrict__ baseAll,
                     float* __restrict__ dw, unsigned* maxbits, int NB, int N, int E) {
  __shared__ float acc[BSZ];
  int tid = threadIdx.x, b = blockIdx.x;
  int bstart = baseAll[(NB + b) * NWG] - E;
  int bend = (b + 1 < NB) ? baseAll[(NB + b + 1) * NWG] - E : E;
  if (tid < BSZ) acc[tid] = 0.f;
  __syncthreads();
  for (int k = bstart + tid; k < bend; k += 256) {
    unsigned p = gS[k];
    atomicAdd(&acc[p >> 16], __half2float(__ushort_as_half((unsigned short)(p & 0xFFFFu))));
  }
  __syncthreads();
  float m = 0.f;
  if (tid < BSZ) {
    int node = b * BSZ + tid;
    if (node < N) { dw[node] = acc[tid]; m = acc[tid]; }
  }
  for (int mm = 32; mm; mm >>= 1) m = fmaxf(m, __shfl_xor(m, mm, 64));
  if ((tid & 63) == 0) atomicMax(maxbits, __float_as_uint(m));
}

// ------- g0 = dinv[i] * (x @ W1) row, stored fp8 e4m3 (wave per row) -------
__global__ void k_gemm1(const float* __restrict__ x, const float* __restrict__ W1,
                        const float* __restrict__ dinv, unsigned char* __restrict__ g0, int N) {
  int lane = threadIdx.x & 63;
  int wid = (blockIdx.x * blockDim.x + threadIdx.x) >> 6;
  int nw = (gridDim.x * blockDim.x) >> 6;
  float w[F_IN];
#pragma unroll
  for (int k = 0; k < F_IN; ++k) w[k] = W1[k * F_HID + lane];
  for (int i = wid; i < N; i += nw) {
    float xa = x[(size_t)i * F_IN + lane];
    float xb = x[(size_t)i * F_IN + 64 + lane];
    float acc0 = 0.f, acc1 = 0.f;
#pragma unroll
    for (int k = 0; k < 64; ++k) {
      float xk0 = __int_as_float(__builtin_amdgcn_readlane(__float_as_int(xa), k));
      float xk1 = __int_as_float(__builtin_amdgcn_readlane(__float_as_int(xb), k));
      acc0 = fmaf(xk0, w[k], acc0);
      acc1 = fmaf(xk1, w[64 + k], acc1);
    }
    g0[(size_t)i * F_HID + lane] = f32_to_fp8((acc0 + acc1) * dinv[i]);
  }
}

// ------- layer-1 agg: wave per node; 8 edge-slots x 8 lanes x 8 features -------
__global__ void k_agg1(const unsigned char* __restrict__ g0, const float* __restrict__ dinv,
                       const int* __restrict__ off, const int2* __restrict__ csr,
                       const float* __restrict__ b1, const float* __restrict__ W2,
                       float* __restrict__ u, int N) {
  int lane = threadIdx.x & 63;
  int grp = lane >> 3;        // edge slot 0..7
  int l8  = lane & 7;         // feature octet 0..7 (features 8*l8 .. 8*l8+7)
  int i = (blockIdx.x * blockDim.x + threadIdx.x) >> 6;
  if (i >= N) return;
  const uint2* g0v = (const uint2*)g0;
  float acc[8] = {0.f, 0.f, 0.f, 0.f, 0.f, 0.f, 0.f, 0.f};
  if (grp == 0) {             // self contribution once (group 0)
    uint2 rv = g0v[(size_t)i * 8 + l8];
    f32x2 c0 = __builtin_amdgcn_cvt_pk_f32_fp8(rv.x, false);
    f32x2 c1 = __builtin_amdgcn_cvt_pk_f32_fp8(rv.x, true);
    f32x2 c2 = __builtin_amdgcn_cvt_pk_f32_fp8(rv.y, false);
    f32x2 c3 = __builtin_amdgcn_cvt_pk_f32_fp8(rv.y, true);
    acc[0] += c0.x; acc[1] += c0.y; acc[2] += c1.x; acc[3] += c1.y;
    acc[4] += c2.x; acc[5] += c2.y; acc[6] += c3.x; acc[7] += c3.y;
  }
  int p0 = off[i], p1 = off[i + 1];
  for (int p = p0; p < p1; p += 64) {
    int m = min(p1 - p, 64);
    int2 ed = make_int2(0, 0);
    if (lane < m) ed = csr[p + lane];
#pragma unroll
    for (int jj = 0; jj < 8; ++jj) {
      int j = jj * 8 + grp;                       // this slot's edge index in batch
      int s = __shfl(ed.x, j, 64);
      float w = __int_as_float(__shfl(ed.y, j, 64));
      if (j < m) {
        uint2 rv = g0v[(size_t)s * 8 + l8];
        f32x2 c0 = __builtin_amdgcn_cvt_pk_f32_fp8(rv.x, false);
        f32x2 c1 = __builtin_amdgcn_cvt_pk_f32_fp8(rv.x, true);
        f32x2 c2 = __builtin_amdgcn_cvt_pk_f32_fp8(rv.y, false);
        f32x2 c3 = __builtin_amdgcn_cvt_pk_f32_fp8(rv.y, true);
        acc[0] = fmaf(w, c0.x, acc[0]); acc[1] = fmaf(w, c0.y, acc[1]);
        acc[2] = fmaf(w, c1.x, acc[2]); acc[3] = fmaf(w, c1.y, acc[3]);
        acc[4] = fmaf(w, c2.x, acc[4]); acc[5] = fmaf(w, c2.y, acc[5]);
        acc[6] = fmaf(w, c3.x, acc[6]); acc[7] = fmaf(w, c3.y, acc[7]);
      }
    }
  }
  // fold the 8 edge slots (lane bits 3..5)
#pragma unroll
  for (int k = 0; k < 8; ++k) {
    acc[k] += __shfl_xor(acc[k], 8, 64);
    acc[k] += __shfl_xor(acc[k], 16, 64);
    acc[k] += __shfl_xor(acc[k], 32, 64);
  }
  float di = dinv[i];
  float pdt = 0.f;
#pragma unroll
  for (int k = 0; k < 8; ++k) {
    int f = l8 * 8 + k;
    float h = fmaxf(di * acc[k] + b1[f], 0.f);
    pdt = fmaf(h, W2[f], pdt);
  }
  pdt += __shfl_xor(pdt, 1, 64);
  pdt += __shfl_xor(pdt, 2, 64);
  pdt += __shfl_xor(pdt, 4, 64);
  if (lane == 0) u[i] = di * pdt;
}

// ------- layer-2 agg + final: 2 nodes per wave (32-lane groups) -------
__global__ void k_agg2_final(const float* __restrict__ u, const float* __restrict__ dinv,
                             const int* __restrict__ off, const int2* __restrict__ csr,
                             const float* __restrict__ b2, const float* __restrict__ dw,
                             const unsigned* __restrict__ maxbits,
                             float* __restrict__ out, int N) {
  int lane32 = threadIdx.x & 31;
  int i = blockIdx.x * 8 + (threadIdx.x >> 5);   // 8 nodes per 256-thread block
  if (i >= N) return;
  float acc = (lane32 == 0) ? u[i] : 0.f;        // self (u_i)
  int p0 = off[i], p1 = off[i + 1];
  for (int p = p0 + lane32; p < p1; p += 32) {
    int2 ed = csr[p];
    acc = fmaf(__int_as_float(ed.y), u[ed.x], acc);
  }
  for (int mm = 16; mm; mm >>= 1) acc += __shfl_xor(acc, mm, 64);
  if (lane32 == 0) {
    float md = __uint_as_float(*maxbits);
    float z = dinv[i] * acc + b2[0];
    float sc = 1.0f / (1.0f + expf(-z));
    out[i] = sc * (1.0f + dw[i] / md);
  }
}

extern "C" void kernel_launch(void* const* d_in, const int* in_sizes, int n_in,
                              void* d_out, int out_size, void* d_ws, size_t ws_size,
                              hipStream_t stream) {
  const float* x  = (const float*)d_in[0];
  const int*   ei = (const int*)d_in[1];
  const float* ew = (const float*)d_in[2];
  const float* W1 = (const float*)d_in[3];
  const float* b1 = (const float*)d_in[4];
  const float* W2 = (const float*)d_in[5];
  const float* b2 = (const float*)d_in[6];
  float* out = (float*)d_out;

  int N = out_size;      // 100000
  int E = in_sizes[2];   // 3200000
  const int* src = ei;
  const int* dst = ei + E;

  int NB = (N + BSZ - 1) >> BSH;        // 782
  int TOT = 2 * NB * NWG;               // 800768
  int SB = (TOT + 1023) >> 10;          // 782 (<=1024)
  size_t shmem = (size_t)(2 * NB) * sizeof(int);

  char* w8 = (char*)d_ws;
  int2*     gD      = (int2*)w8;                         // E int2  (becomes CSR in place)
  unsigned* gS      = (unsigned*)(gD + E);               // E u32
  int*      cntAll  = (int*)(gS + E);                    // TOT i  (scanned in place)
  int*      partials= cntAll + TOT;                      // 1024 i
  int*      off     = partials + 1024;                   // N+1 i
  float*    dinv    = (float*)(off + N + 1);             // N f
  float*    dw      = dinv + N;                          // N f
  float*    u       = dw + N;                            // N f
  unsigned* maxbits = (unsigned*)(u + N);                // 1 u
  unsigned char* g0 = (unsigned char*)(maxbits + 2);     // N*64 fp8

  k_count<<<NWG, PT, shmem, stream>>>(src, dst, cntAll, NB, E);
  k_scanA<<<SB, 1024, 0, stream>>>(cntAll, partials, TOT);
  k_scanB<<<1, 1024, 0, stream>>>(partials, SB, maxbits);
  k_scanC<<<SB, 1024, 0, stream>>>(cntAll, partials, TOT);
  k_part<<<NWG, PT, shmem, stream>>>(src, dst, ew, cntAll, gD, gS, NB, E);
  k_csr<<<NB, 256, 0, stream>>>(gD, cntAll, off, dinv, NB, N, E);
  k_dw<<<NB, 256, 0, stream>>>(gS, cntAll, dw, maxbits, NB, N, E);
  k_gemm1<<<1024, 256, 0, stream>>>(x, W1, dinv, g0, N);
  k_agg1<<<(N * 64 + 255) / 256, 256, 0, stream>>>(g0, dinv, off, gD, b1, W2, u, N);
  k_agg2_final<<<(N + 7) / 8, 256, 0, stream>>>(u, dinv, off, gD, b2, dw, maxbits, out, N);
}

// Round 9
// 303.167 us; speedup vs baseline: 4.1968x; 1.2212x over previous
//
#include <hip/hip_runtime.h>
#include <hip/hip_fp16.h>
#include <math.h>

#define F_IN 128
#define F_HID 64
#define NWG 512      // partition chunks (= blocks of k_count/k_part)
#define PT 1024      // threads per partition block (16 waves -> full occupancy)
#define BSH 7        // bucket shift (128 nodes per bucket)
#define BSZ 128
#define SEGCAP 6144  // max edges per bucket staged in LDS (mean 4096, ~32 sigma headroom)

typedef float f32x2 __attribute__((ext_vector_type(2)));
typedef float f32x4 __attribute__((ext_vector_type(4)));
typedef __bf16 bf16x8 __attribute__((ext_vector_type(8)));

// ---- fp8 e4m3 (OCP, gfx950 HW cvt) ----
__device__ __forceinline__ unsigned char f32_to_fp8(float v) {
  unsigned r = __builtin_amdgcn_cvt_pk_fp8_f32(v, v, 0, false);
  return (unsigned char)(r & 0xFFu);
}

// ---- f32 -> bf16 RTNE (bit-manip) ----
__device__ __forceinline__ __bf16 f32_bf16(float f) {
  unsigned u = __float_as_uint(f);
  unsigned r = (u + 0x7FFFu + ((u >> 16) & 1u)) >> 16;
  return __builtin_bit_cast(__bf16, (unsigned short)r);
}

// ------- P1: per-(bucket, wg) counts for dst-buckets and src-buckets (LDS only) -------
__global__ void k_count(const int* __restrict__ src, const int* __restrict__ dst,
                        int* __restrict__ cntAll, int NB, int E) {
  extern __shared__ int sh[];
  int* hD = sh;         // NB
  int* hS = sh + NB;    // NB
  int tid = threadIdx.x, w = blockIdx.x;
  for (int k = tid; k < 2 * NB; k += PT) sh[k] = 0;
  __syncthreads();
  int C = (E + NWG - 1) / NWG;
  int e0 = w * C, e1 = min(E, e0 + C);
  for (int e = e0 + tid; e < e1; e += PT) {
    atomicAdd(&hD[dst[e] >> BSH], 1);
    atomicAdd(&hS[src[e] >> BSH], 1);
  }
  __syncthreads();
  for (int b = tid; b < NB; b += PT) {
    cntAll[b * NWG + w] = hD[b];
    cntAll[(NB + b) * NWG + w] = hS[b];
  }
}

// ---------------- flat exclusive scan (in place), 1024-thread blocks ----------------
__global__ void k_scanA(int* __restrict__ data, int* __restrict__ partials, int TOT) {
  __shared__ int lds[1024];
  int tid = threadIdx.x;
  int g = blockIdx.x * 1024 + tid;
  int v = (g < TOT) ? data[g] : 0;
  lds[tid] = v; __syncthreads();
  for (int o = 1; o < 1024; o <<= 1) {
    int t = (tid >= o) ? lds[tid - o] : 0;
    __syncthreads();
    lds[tid] += t;
    __syncthreads();
  }
  if (g < TOT) data[g] = lds[tid] - v;
  if (tid == 1023) partials[blockIdx.x] = lds[1023];
}

__global__ void k_scanB(int* partials, int nb, unsigned* maxbits) {
  __shared__ int lds[1024];
  int tid = threadIdx.x;
  if (tid == 0) *maxbits = 0u;
  int v = (tid < nb) ? partials[tid] : 0;
  lds[tid] = v; __syncthreads();
  for (int o = 1; o < 1024; o <<= 1) {
    int t = (tid >= o) ? lds[tid - o] : 0;
    __syncthreads();
    lds[tid] += t;
    __syncthreads();
  }
  if (tid < nb) partials[tid] = lds[tid] - v;
}

__global__ void k_scanC(int* __restrict__ data, const int* __restrict__ partials, int TOT) {
  int g = blockIdx.x * 1024 + threadIdx.x;
  if (g < TOT) data[g] += partials[g >> 10];
}

// ------- P3: partition edges into dst-buckets (int2) and src-buckets (packed u32) -------
__global__ void k_part(const int* __restrict__ src, const int* __restrict__ dst,
                       const float* __restrict__ ew, const int* __restrict__ baseAll,
                       int2* __restrict__ gD, unsigned* __restrict__ gS, int NB, int E) {
  extern __shared__ int sh[];
  int* cD = sh;
  int* cS = sh + NB;
  int tid = threadIdx.x, w = blockIdx.x;
  for (int b = tid; b < NB; b += PT) {
    cD[b] = baseAll[b * NWG + w];
    cS[b] = baseAll[(NB + b) * NWG + w] - E;
  }
  __syncthreads();
  int C = (E + NWG - 1) / NWG;
  int e0 = w * C, e1 = min(E, e0 + C);
  for (int e = e0 + tid; e < e1; e += PT) {
    int s = src[e], d = dst[e];
    float wv = ew[e];
    int pD = atomicAdd(&cD[d >> BSH], 1);
    gD[pD] = make_int2(s | ((d & (BSZ - 1)) << 24), __float_as_int(wv));
    int pS = atomicAdd(&cS[s >> BSH], 1);
    unsigned hb = (unsigned)__half_as_ushort(__float2half(wv));
    gS[pS] = ((unsigned)(s & (BSZ - 1)) << 16) | hb;
  }
}

// ------- P4a: per-dst-bucket local counting sort -> CSR (in place) + off + dinv -------
__global__ void k_csr(int2* __restrict__ gD, const int* __restrict__ baseAll,
                      int* __restrict__ off, float* __restrict__ dinv,
                      int NB, int N, int E) {
  __shared__ int2 seg[SEGCAP];
  __shared__ int hist[BSZ];
  __shared__ int curs[BSZ];
  __shared__ float degf[BSZ];
  int tid = threadIdx.x, b = blockIdx.x;
  int bstart = baseAll[b * NWG];
  int bend = (b + 1 < NB) ? baseAll[(b + 1) * NWG] : E;
  int cnt = bend - bstart;
  for (int k = tid; k < cnt; k += 256) seg[k] = gD[bstart + k];
  if (tid < BSZ) { hist[tid] = 0; degf[tid] = 0.f; }
  __syncthreads();
  for (int k = tid; k < cnt; k += 256) {
    int dl = seg[k].x >> 24;
    atomicAdd(&hist[dl], 1);
    atomicAdd(&degf[dl], __int_as_float(seg[k].y));
  }
  __syncthreads();
  int v = (tid < BSZ) ? hist[tid] : 0;
  for (int o = 1; o < BSZ; o <<= 1) {
    int t = (tid < BSZ && tid >= o) ? hist[tid - o] : 0;
    __syncthreads();
    if (tid < BSZ) hist[tid] += t;
    __syncthreads();
  }
  if (tid < BSZ) {
    int excl = hist[tid] - v;
    curs[tid] = excl;
    int node = b * BSZ + tid;
    if (node < N) {
      off[node] = bstart + excl;
      dinv[node] = rsqrtf(1.0f + degf[tid]);
    }
  }
  if (b == NB - 1 && tid == 0) off[N] = E;
  __syncthreads();
  for (int k = tid; k < cnt; k += 256) {
    int2 ev = seg[k];
    int dl = ev.x >> 24;
    int slot = atomicAdd(&curs[dl], 1);
    gD[bstart + slot] = make_int2(ev.x & 0xFFFFFF, ev.y);
  }
}

// ------- P4b: per-src-bucket weighted out-degree (dw) + global max -------
__global__ void k_dw(const unsigned* __restrict__ gS, const int* __restrict__ baseAll,
                     float* __restrict__ dw, unsigned* maxbits, int NB, int N, int E) {
  __shared__ float acc[BSZ];
  int tid = threadIdx.x, b = blockIdx.x;
  int bstart = baseAll[(NB + b) * NWG] - E;
  int bend = (b + 1 < NB) ? baseAll[(NB + b + 1) * NWG] - E : E;
  if (tid < BSZ) acc[tid] = 0.f;
  __syncthreads();
  for (int k = bstart + tid; k < bend; k += 256) {
    unsigned p = gS[k];
    atomicAdd(&acc[p >> 16], __half2float(__ushort_as_half((unsigned short)(p & 0xFFFFu))));
  }
  __syncthreads();
  float m = 0.f;
  if (tid < BSZ) {
    int node = b * BSZ + tid;
    if (node < N) { dw[node] = acc[tid]; m = acc[tid]; }
  }
  for (int mm = 32; mm; mm >>= 1) m = fmaxf(m, __shfl_xor(m, mm, 64));
  if ((tid & 63) == 0) atomicMax(maxbits, __float_as_uint(m));
}

// ------- g0 = dinv[i] * (x @ W1) row, MFMA 16x16x32 bf16, stored fp8 e4m3 -------
// A: row=l&15, k=(l>>4)*8+i ; B: col=l&15, k=(l>>4)*8+i ; D: col=l&15, row=(l>>4)*4+reg
__global__ void k_gemm1(const float* __restrict__ x, const float* __restrict__ W1,
                        const float* __restrict__ dinv, unsigned char* __restrict__ g0, int N) {
  int lane = threadIdx.x & 63;
  int wid = (blockIdx.x * blockDim.x + threadIdx.x) >> 6;
  int nw = (gridDim.x * blockDim.x) >> 6;
  int l16 = lane & 15, lh = lane >> 4;
  // B fragments (W1), loaded once per wave: b[cb][kf]
  bf16x8 bfrag[4][4];
#pragma unroll
  for (int cb = 0; cb < 4; ++cb)
#pragma unroll
    for (int kf = 0; kf < 4; ++kf)
#pragma unroll
      for (int i = 0; i < 8; ++i) {
        int k = kf * 32 + lh * 8 + i;
        bfrag[cb][kf][i] = f32_bf16(W1[k * F_HID + cb * 16 + l16]);
      }
  int ntiles = (N + 15) >> 4;
  for (int t = wid; t < ntiles; t += nw) {
    int rowbase = t << 4;
    int row = min(rowbase + l16, N - 1);
    bf16x8 afrag[4];
#pragma unroll
    for (int kf = 0; kf < 4; ++kf) {
      const f32x4* xp = (const f32x4*)(x + (size_t)row * F_IN + kf * 32 + lh * 8);
      f32x4 v0 = xp[0], v1 = xp[1];
#pragma unroll
      for (int i = 0; i < 4; ++i) afrag[kf][i] = f32_bf16(v0[i]);
#pragma unroll
      for (int i = 0; i < 4; ++i) afrag[kf][4 + i] = f32_bf16(v1[i]);
    }
    f32x4 acc[4] = {{0.f,0.f,0.f,0.f},{0.f,0.f,0.f,0.f},{0.f,0.f,0.f,0.f},{0.f,0.f,0.f,0.f}};
#pragma unroll
    for (int cb = 0; cb < 4; ++cb)
#pragma unroll
      for (int kf = 0; kf < 4; ++kf)
        acc[cb] = __builtin_amdgcn_mfma_f32_16x16x32_bf16(afrag[kf], bfrag[cb][kf], acc[cb], 0, 0, 0);
    if (rowbase + 16 <= N) {
      f32x4 dv = *(const f32x4*)(dinv + rowbase + lh * 4);
#pragma unroll
      for (int cb = 0; cb < 4; ++cb)
#pragma unroll
        for (int r = 0; r < 4; ++r) {
          int rr = rowbase + lh * 4 + r;
          g0[(size_t)rr * F_HID + cb * 16 + l16] = f32_to_fp8(acc[cb][r] * dv[r]);
        }
    } else {  // tail tile (not hit for N%16==0)
#pragma unroll
      for (int cb = 0; cb < 4; ++cb)
#pragma unroll
        for (int r = 0; r < 4; ++r) {
          int rr = rowbase + lh * 4 + r;
          if (rr < N)
            g0[(size_t)rr * F_HID + cb * 16 + l16] = f32_to_fp8(acc[cb][r] * dinv[rr]);
        }
    }
  }
}

// ------- layer-1 agg: wave per node; 8 edge-slots x 8 lanes x 8 features -------
__global__ void k_agg1(const unsigned char* __restrict__ g0, const float* __restrict__ dinv,
                       const int* __restrict__ off, const int2* __restrict__ csr,
                       const float* __restrict__ b1, const float* __restrict__ W2,
                       float* __restrict__ u, int N) {
  int lane = threadIdx.x & 63;
  int grp = lane >> 3;        // edge slot 0..7
  int l8  = lane & 7;         // feature octet 0..7 (features 8*l8 .. 8*l8+7)
  int i = (blockIdx.x * blockDim.x + threadIdx.x) >> 6;
  if (i >= N) return;
  const uint2* g0v = (const uint2*)g0;
  float acc[8] = {0.f, 0.f, 0.f, 0.f, 0.f, 0.f, 0.f, 0.f};
  if (grp == 0) {             // self contribution once (group 0)
    uint2 rv = g0v[(size_t)i * 8 + l8];
    f32x2 c0 = __builtin_amdgcn_cvt_pk_f32_fp8(rv.x, false);
    f32x2 c1 = __builtin_amdgcn_cvt_pk_f32_fp8(rv.x, true);
    f32x2 c2 = __builtin_amdgcn_cvt_pk_f32_fp8(rv.y, false);
    f32x2 c3 = __builtin_amdgcn_cvt_pk_f32_fp8(rv.y, true);
    acc[0] += c0.x; acc[1] += c0.y; acc[2] += c1.x; acc[3] += c1.y;
    acc[4] += c2.x; acc[5] += c2.y; acc[6] += c3.x; acc[7] += c3.y;
  }
  int p0 = off[i], p1 = off[i + 1];
  for (int p = p0; p < p1; p += 64) {
    int m = min(p1 - p, 64);
    int2 ed = make_int2(0, 0);
    if (lane < m) ed = csr[p + lane];
#pragma unroll
    for (int jj = 0; jj < 8; ++jj) {
      int j = jj * 8 + grp;                       // this slot's edge index in batch
      int s = __shfl(ed.x, j, 64);
      float w = __int_as_float(__shfl(ed.y, j, 64));
      if (j < m) {
        uint2 rv = g0v[(size_t)s * 8 + l8];
        f32x2 c0 = __builtin_amdgcn_cvt_pk_f32_fp8(rv.x, false);
        f32x2 c1 = __builtin_amdgcn_cvt_pk_f32_fp8(rv.x, true);
        f32x2 c2 = __builtin_amdgcn_cvt_pk_f32_fp8(rv.y, false);
        f32x2 c3 = __builtin_amdgcn_cvt_pk_f32_fp8(rv.y, true);
        acc[0] = fmaf(w, c0.x, acc[0]); acc[1] = fmaf(w, c0.y, acc[1]);
        acc[2] = fmaf(w, c1.x, acc[2]); acc[3] = fmaf(w, c1.y, acc[3]);
        acc[4] = fmaf(w, c2.x, acc[4]); acc[5] = fmaf(w, c2.y, acc[5]);
        acc[6] = fmaf(w, c3.x, acc[6]); acc[7] = fmaf(w, c3.y, acc[7]);
      }
    }
  }
  // fold the 8 edge slots (lane bits 3..5)
#pragma unroll
  for (int k = 0; k < 8; ++k) {
    acc[k] += __shfl_xor(acc[k], 8, 64);
    acc[k] += __shfl_xor(acc[k], 16, 64);
    acc[k] += __shfl_xor(acc[k], 32, 64);
  }
  float di = dinv[i];
  float pdt = 0.f;
#pragma unroll
  for (int k = 0; k < 8; ++k) {
    int f = l8 * 8 + k;
    float h = fmaxf(di * acc[k] + b1[f], 0.f);
    pdt = fmaf(h, W2[f], pdt);
  }
  pdt += __shfl_xor(pdt, 1, 64);
  pdt += __shfl_xor(pdt, 2, 64);
  pdt += __shfl_xor(pdt, 4, 64);
  if (lane == 0) u[i] = di * pdt;
}

// ------- layer-2 agg + final: 2 nodes per wave (32-lane groups) -------
__global__ void k_agg2_final(const float* __restrict__ u, const float* __restrict__ dinv,
                             const int* __restrict__ off, const int2* __restrict__ csr,
                             const float* __restrict__ b2, const float* __restrict__ dw,
                             const unsigned* __restrict__ maxbits,
                             float* __restrict__ out, int N) {
  int lane32 = threadIdx.x & 31;
  int i = blockIdx.x * 8 + (threadIdx.x >> 5);   // 8 nodes per 256-thread block
  if (i >= N) return;
  float acc = (lane32 == 0) ? u[i] : 0.f;        // self (u_i)
  int p0 = off[i], p1 = off[i + 1];
  for (int p = p0 + lane32; p < p1; p += 32) {
    int2 ed = csr[p];
    acc = fmaf(__int_as_float(ed.y), u[ed.x], acc);
  }
  for (int mm = 16; mm; mm >>= 1) acc += __shfl_xor(acc, mm, 64);
  if (lane32 == 0) {
    float md = __uint_as_float(*maxbits);
    float z = dinv[i] * acc + b2[0];
    float sc = 1.0f / (1.0f + expf(-z));
    out[i] = sc * (1.0f + dw[i] / md);
  }
}

extern "C" void kernel_launch(void* const* d_in, const int* in_sizes, int n_in,
                              void* d_out, int out_size, void* d_ws, size_t ws_size,
                              hipStream_t stream) {
  const float* x  = (const float*)d_in[0];
  const int*   ei = (const int*)d_in[1];
  const float* ew = (const float*)d_in[2];
  const float* W1 = (const float*)d_in[3];
  const float* b1 = (const float*)d_in[4];
  const float* W2 = (const float*)d_in[5];
  const float* b2 = (const float*)d_in[6];
  float* out = (float*)d_out;

  int N = out_size;      // 100000
  int E = in_sizes[2];   // 3200000
  const int* src = ei;
  const int* dst = ei + E;

  int NB = (N + BSZ - 1) >> BSH;        // 782
  int TOT = 2 * NB * NWG;               // 800768
  int SB = (TOT + 1023) >> 10;          // 782 (<=1024)
  size_t shmem = (size_t)(2 * NB) * sizeof(int);

  char* w8 = (char*)d_ws;
  int2*     gD      = (int2*)w8;                         // E int2  (becomes CSR in place)
  unsigned* gS      = (unsigned*)(gD + E);               // E u32
  int*      cntAll  = (int*)(gS + E);                    // TOT i  (scanned in place)
  int*      partials= cntAll + TOT;                      // 1024 i
  int*      off     = partials + 1024;                   // N+1 i
  float*    dinv    = (float*)(off + N + 1);             // N f
  float*    dw      = dinv + N;                          // N f
  float*    u       = dw + N;                            // N f
  unsigned* maxbits = (unsigned*)(u + N);                // 1 u
  unsigned char* g0 = (unsigned char*)(maxbits + 2);     // N*64 fp8

  k_count<<<NWG, PT, shmem, stream>>>(src, dst, cntAll, NB, E);
  k_scanA<<<SB, 1024, 0, stream>>>(cntAll, partials, TOT);
  k_scanB<<<1, 1024, 0, stream>>>(partials, SB, maxbits);
  k_scanC<<<SB, 1024, 0, stream>>>(cntAll, partials, TOT);
  k_part<<<NWG, PT, shmem, stream>>>(src, dst, ew, cntAll, gD, gS, NB, E);
  k_csr<<<NB, 256, 0, stream>>>(gD, cntAll, off, dinv, NB, N, E);
  k_dw<<<NB, 256, 0, stream>>>(gS, cntAll, dw, maxbits, NB, N, E);
  k_gemm1<<<256, 256, 0, stream>>>(x, W1, dinv, g0, N);
  k_agg1<<<(N * 64 + 255) / 256, 256, 0, stream>>>(g0, dinv, off, gD, b1, W2, u, N);
  k_agg2_final<<<(N + 7) / 8, 256, 0, stream>>>(u, dinv, off, gD, b2, dw, maxbits, out, N);
}

// Round 10
// 270.539 us; speedup vs baseline: 4.7030x; 1.1206x over previous
//
#include <hip/hip_runtime.h>
#include <hip/hip_fp16.h>
#include <math.h>

#define F_IN 128
#define F_HID 64
#define NWG 256      // partition chunks (= blocks of k_count/k_part)
#define PT 1024      // threads per partition block
#define BSH 7        // dst bucket shift (128 nodes per bucket)
#define BSZ 128
#define BSHS 10      // src bucket shift (1024 nodes per bucket, feeds k_dw LDS acc)
#define BSZS 1024
#define SEGCAP 6144  // max edges per dst-bucket staged in LDS (mean 4096)

typedef float f32x2 __attribute__((ext_vector_type(2)));
typedef float f32x4 __attribute__((ext_vector_type(4)));
typedef __bf16 bf16x8 __attribute__((ext_vector_type(8)));

// ---- fp8 e4m3 (OCP, gfx950 HW cvt) ----
__device__ __forceinline__ unsigned char f32_to_fp8(float v) {
  unsigned r = __builtin_amdgcn_cvt_pk_fp8_f32(v, v, 0, false);
  return (unsigned char)(r & 0xFFu);
}

// ---- f32 -> bf16 RTNE (bit-manip) ----
__device__ __forceinline__ __bf16 f32_bf16(float f) {
  unsigned u = __float_as_uint(f);
  unsigned r = (u + 0x7FFFu + ((u >> 16) & 1u)) >> 16;
  return __builtin_bit_cast(__bf16, (unsigned short)r);
}

// ------- P1: per-(bucket, wg) counts, dst-buckets (128) and src-buckets (1024) -------
__global__ void k_count(const int* __restrict__ src, const int* __restrict__ dst,
                        int* __restrict__ cntAll, int NBD, int NBS, int E) {
  extern __shared__ int sh[];
  int* hD = sh;          // NBD
  int* hS = sh + NBD;    // NBS
  int tid = threadIdx.x, w = blockIdx.x;
  for (int k = tid; k < NBD + NBS; k += PT) sh[k] = 0;
  __syncthreads();
  int C = (E + NWG - 1) / NWG;
  int e0 = w * C, e1 = min(E, e0 + C);
  for (int e = e0 + tid; e < e1; e += PT) {
    atomicAdd(&hD[dst[e] >> BSH], 1);
    atomicAdd(&hS[src[e] >> BSHS], 1);
  }
  __syncthreads();
  for (int b = tid; b < NBD; b += PT) cntAll[b * NWG + w] = hD[b];
  for (int b = tid; b < NBS; b += PT) cntAll[(NBD + b) * NWG + w] = hS[b];
}

// ---------------- flat exclusive scan (in place), 1024-thread blocks ----------------
__global__ void k_scanA(int* __restrict__ data, int* __restrict__ partials, int TOT) {
  __shared__ int lds[1024];
  int tid = threadIdx.x;
  int g = blockIdx.x * 1024 + tid;
  int v = (g < TOT) ? data[g] : 0;
  lds[tid] = v; __syncthreads();
  for (int o = 1; o < 1024; o <<= 1) {
    int t = (tid >= o) ? lds[tid - o] : 0;
    __syncthreads();
    lds[tid] += t;
    __syncthreads();
  }
  if (g < TOT) data[g] = lds[tid] - v;
  if (tid == 1023) partials[blockIdx.x] = lds[1023];
}

__global__ void k_scanB(int* partials, int nb, unsigned* maxbits) {
  __shared__ int lds[1024];
  int tid = threadIdx.x;
  if (tid == 0) *maxbits = 0u;
  int v = (tid < nb) ? partials[tid] : 0;
  lds[tid] = v; __syncthreads();
  for (int o = 1; o < 1024; o <<= 1) {
    int t = (tid >= o) ? lds[tid - o] : 0;
    __syncthreads();
    lds[tid] += t;
    __syncthreads();
  }
  if (tid < nb) partials[tid] = lds[tid] - v;
}

__global__ void k_scanC(int* __restrict__ data, const int* __restrict__ partials, int TOT) {
  int g = blockIdx.x * 1024 + threadIdx.x;
  if (g < TOT) data[g] += partials[g >> 10];
}

// ------- P3: partition edges into dst-buckets (int2) and src-buckets (packed u32) -------
__global__ void k_part(const int* __restrict__ src, const int* __restrict__ dst,
                       const float* __restrict__ ew, const int* __restrict__ baseAll,
                       int2* __restrict__ gD, unsigned* __restrict__ gS,
                       int NBD, int NBS, int E) {
  extern __shared__ int sh[];
  int* cD = sh;
  int* cS = sh + NBD;
  int tid = threadIdx.x, w = blockIdx.x;
  for (int b = tid; b < NBD; b += PT) cD[b] = baseAll[b * NWG + w];
  for (int b = tid; b < NBS; b += PT) cS[b] = baseAll[(NBD + b) * NWG + w] - E;
  __syncthreads();
  int C = (E + NWG - 1) / NWG;
  int e0 = w * C, e1 = min(E, e0 + C);
  for (int e = e0 + tid; e < e1; e += PT) {
    int s = src[e], d = dst[e];
    float wv = ew[e];
    int pD = atomicAdd(&cD[d >> BSH], 1);
    gD[pD] = make_int2(s | ((d & (BSZ - 1)) << 24), __float_as_int(wv));
    int pS = atomicAdd(&cS[s >> BSHS], 1);
    unsigned hb = (unsigned)__half_as_ushort(__float2half(wv));
    gS[pS] = ((unsigned)(s & (BSZS - 1)) << 16) | hb;
  }
}

// ------- P4a: per-dst-bucket local counting sort -> CSR (in place) + off + dinv -------
__global__ void k_csr(int2* __restrict__ gD, const int* __restrict__ baseAll,
                      int* __restrict__ off, float* __restrict__ dinv,
                      int NBD, int N, int E) {
  __shared__ int2 seg[SEGCAP];
  __shared__ int hist[BSZ];
  __shared__ int curs[BSZ];
  __shared__ float degf[BSZ];
  int tid = threadIdx.x, b = blockIdx.x;
  int bstart = baseAll[b * NWG];
  int bend = (b + 1 < NBD) ? baseAll[(b + 1) * NWG] : E;
  int cnt = bend - bstart;
  for (int k = tid; k < cnt; k += 256) seg[k] = gD[bstart + k];
  if (tid < BSZ) { hist[tid] = 0; degf[tid] = 0.f; }
  __syncthreads();
  for (int k = tid; k < cnt; k += 256) {
    int dl = seg[k].x >> 24;
    atomicAdd(&hist[dl], 1);
    atomicAdd(&degf[dl], __int_as_float(seg[k].y));
  }
  __syncthreads();
  int v = (tid < BSZ) ? hist[tid] : 0;
  for (int o = 1; o < BSZ; o <<= 1) {
    int t = (tid < BSZ && tid >= o) ? hist[tid - o] : 0;
    __syncthreads();
    if (tid < BSZ) hist[tid] += t;
    __syncthreads();
  }
  if (tid < BSZ) {
    int excl = hist[tid] - v;
    curs[tid] = excl;
    int node = b * BSZ + tid;
    if (node < N) {
      off[node] = bstart + excl;
      dinv[node] = rsqrtf(1.0f + degf[tid]);
    }
  }
  if (b == NBD - 1 && tid == 0) off[N] = E;
  __syncthreads();
  for (int k = tid; k < cnt; k += 256) {
    int2 ev = seg[k];
    int dl = ev.x >> 24;
    int slot = atomicAdd(&curs[dl], 1);
    gD[bstart + slot] = make_int2(ev.x & 0xFFFFFF, ev.y);
  }
}

// ------- P4b: per-src-bucket (1024 nodes) weighted out-degree (dw) + global max -------
__global__ void k_dw(const unsigned* __restrict__ gS, const int* __restrict__ baseAll,
                     float* __restrict__ dw, unsigned* maxbits,
                     int NBD, int NBS, int N, int E) {
  __shared__ float acc[BSZS];
  int tid = threadIdx.x, b = blockIdx.x;
  int bstart = baseAll[(NBD + b) * NWG] - E;
  int bend = (b + 1 < NBS) ? baseAll[(NBD + b + 1) * NWG] - E : E;
  acc[tid] = 0.f;
  __syncthreads();
  for (int k = bstart + tid; k < bend; k += BSZS) {
    unsigned p = gS[k];
    atomicAdd(&acc[p >> 16], __half2float(__ushort_as_half((unsigned short)(p & 0xFFFFu))));
  }
  __syncthreads();
  float m = 0.f;
  int node = b * BSZS + tid;
  if (node < N) { dw[node] = acc[tid]; m = acc[tid]; }
  for (int mm = 32; mm; mm >>= 1) m = fmaxf(m, __shfl_xor(m, mm, 64));
  if ((tid & 63) == 0) atomicMax(maxbits, __float_as_uint(m));
}

// ------- g0 = dinv[i] * (x @ W1) row, MFMA 16x16x32 bf16, stored fp8 e4m3 -------
// A: row=l&15, k=(l>>4)*8+i ; B: col=l&15, k=(l>>4)*8+i ; D: col=l&15, row=(l>>4)*4+reg
__global__ void k_gemm1(const float* __restrict__ x, const float* __restrict__ W1,
                        const float* __restrict__ dinv, unsigned char* __restrict__ g0, int N) {
  int lane = threadIdx.x & 63;
  int wid = (blockIdx.x * blockDim.x + threadIdx.x) >> 6;
  int nw = (gridDim.x * blockDim.x) >> 6;
  int l16 = lane & 15, lh = lane >> 4;
  bf16x8 bfrag[4][4];
#pragma unroll
  for (int cb = 0; cb < 4; ++cb)
#pragma unroll
    for (int kf = 0; kf < 4; ++kf)
#pragma unroll
      for (int i = 0; i < 8; ++i) {
        int k = kf * 32 + lh * 8 + i;
        bfrag[cb][kf][i] = f32_bf16(W1[k * F_HID + cb * 16 + l16]);
      }
  int ntiles = (N + 15) >> 4;
  for (int t = wid; t < ntiles; t += nw) {
    int rowbase = t << 4;
    int row = min(rowbase + l16, N - 1);
    bf16x8 afrag[4];
#pragma unroll
    for (int kf = 0; kf < 4; ++kf) {
      const f32x4* xp = (const f32x4*)(x + (size_t)row * F_IN + kf * 32 + lh * 8);
      f32x4 v0 = xp[0], v1 = xp[1];
#pragma unroll
      for (int i = 0; i < 4; ++i) afrag[kf][i] = f32_bf16(v0[i]);
#pragma unroll
      for (int i = 0; i < 4; ++i) afrag[kf][4 + i] = f32_bf16(v1[i]);
    }
    f32x4 acc[4] = {{0.f,0.f,0.f,0.f},{0.f,0.f,0.f,0.f},{0.f,0.f,0.f,0.f},{0.f,0.f,0.f,0.f}};
#pragma unroll
    for (int cb = 0; cb < 4; ++cb)
#pragma unroll
      for (int kf = 0; kf < 4; ++kf)
        acc[cb] = __builtin_amdgcn_mfma_f32_16x16x32_bf16(afrag[kf], bfrag[cb][kf], acc[cb], 0, 0, 0);
    if (rowbase + 16 <= N) {
      f32x4 dv = *(const f32x4*)(dinv + rowbase + lh * 4);
#pragma unroll
      for (int cb = 0; cb < 4; ++cb)
#pragma unroll
        for (int r = 0; r < 4; ++r) {
          int rr = rowbase + lh * 4 + r;
          g0[(size_t)rr * F_HID + cb * 16 + l16] = f32_to_fp8(acc[cb][r] * dv[r]);
        }
    } else {
#pragma unroll
      for (int cb = 0; cb < 4; ++cb)
#pragma unroll
        for (int r = 0; r < 4; ++r) {
          int rr = rowbase + lh * 4 + r;
          if (rr < N)
            g0[(size_t)rr * F_HID + cb * 16 + l16] = f32_to_fp8(acc[cb][r] * dinv[rr]);
        }
    }
  }
}

// ------- layer-1 agg: wave per node; 8 edge-slots x 8 lanes x 8 features -------
__global__ void k_agg1(const unsigned char* __restrict__ g0, const float* __restrict__ dinv,
                       const int* __restrict__ off, const int2* __restrict__ csr,
                       const float* __restrict__ b1, const float* __restrict__ W2,
                       float* __restrict__ u, int N) {
  int lane = threadIdx.x & 63;
  int grp = lane >> 3;        // edge slot 0..7
  int l8  = lane & 7;         // feature octet 0..7
  int i = (blockIdx.x * blockDim.x + threadIdx.x) >> 6;
  if (i >= N) return;
  const uint2* g0v = (const uint2*)g0;
  float acc[8] = {0.f, 0.f, 0.f, 0.f, 0.f, 0.f, 0.f, 0.f};
  if (grp == 0) {             // self contribution once (group 0)
    uint2 rv = g0v[(size_t)i * 8 + l8];
    f32x2 c0 = __builtin_amdgcn_cvt_pk_f32_fp8(rv.x, false);
    f32x2 c1 = __builtin_amdgcn_cvt_pk_f32_fp8(rv.x, true);
    f32x2 c2 = __builtin_amdgcn_cvt_pk_f32_fp8(rv.y, false);
    f32x2 c3 = __builtin_amdgcn_cvt_pk_f32_fp8(rv.y, true);
    acc[0] += c0.x; acc[1] += c0.y; acc[2] += c1.x; acc[3] += c1.y;
    acc[4] += c2.x; acc[5] += c2.y; acc[6] += c3.x; acc[7] += c3.y;
  }
  int p0 = off[i], p1 = off[i + 1];
  for (int p = p0; p < p1; p += 64) {
    int m = min(p1 - p, 64);
    int2 ed = make_int2(0, 0);
    if (lane < m) ed = csr[p + lane];
#pragma unroll
    for (int jj = 0; jj < 8; ++jj) {
      int j = jj * 8 + grp;
      int s = __shfl(ed.x, j, 64);
      float w = __int_as_float(__shfl(ed.y, j, 64));
      if (j < m) {
        uint2 rv = g0v[(size_t)s * 8 + l8];
        f32x2 c0 = __builtin_amdgcn_cvt_pk_f32_fp8(rv.x, false);
        f32x2 c1 = __builtin_amdgcn_cvt_pk_f32_fp8(rv.x, true);
        f32x2 c2 = __builtin_amdgcn_cvt_pk_f32_fp8(rv.y, false);
        f32x2 c3 = __builtin_amdgcn_cvt_pk_f32_fp8(rv.y, true);
        acc[0] = fmaf(w, c0.x, acc[0]); acc[1] = fmaf(w, c0.y, acc[1]);
        acc[2] = fmaf(w, c1.x, acc[2]); acc[3] = fmaf(w, c1.y, acc[3]);
        acc[4] = fmaf(w, c2.x, acc[4]); acc[5] = fmaf(w, c2.y, acc[5]);
        acc[6] = fmaf(w, c3.x, acc[6]); acc[7] = fmaf(w, c3.y, acc[7]);
      }
    }
  }
#pragma unroll
  for (int k = 0; k < 8; ++k) {
    acc[k] += __shfl_xor(acc[k], 8, 64);
    acc[k] += __shfl_xor(acc[k], 16, 64);
    acc[k] += __shfl_xor(acc[k], 32, 64);
  }
  float di = dinv[i];
  float pdt = 0.f;
#pragma unroll
  for (int k = 0; k < 8; ++k) {
    int f = l8 * 8 + k;
    float h = fmaxf(di * acc[k] + b1[f], 0.f);
    pdt = fmaf(h, W2[f], pdt);
  }
  pdt += __shfl_xor(pdt, 1, 64);
  pdt += __shfl_xor(pdt, 2, 64);
  pdt += __shfl_xor(pdt, 4, 64);
  if (lane == 0) u[i] = di * pdt;
}

// ------- layer-2 agg + final: 2 nodes per wave (32-lane groups) -------
__global__ void k_agg2_final(const float* __restrict__ u, const float* __restrict__ dinv,
                             const int* __restrict__ off, const int2* __restrict__ csr,
                             const float* __restrict__ b2, const float* __restrict__ dw,
                             const unsigned* __restrict__ maxbits,
                             float* __restrict__ out, int N) {
  int lane32 = threadIdx.x & 31;
  int i = blockIdx.x * 8 + (threadIdx.x >> 5);
  if (i >= N) return;
  float acc = (lane32 == 0) ? u[i] : 0.f;
  int p0 = off[i], p1 = off[i + 1];
  for (int p = p0 + lane32; p < p1; p += 32) {
    int2 ed = csr[p];
    acc = fmaf(__int_as_float(ed.y), u[ed.x], acc);
  }
  for (int mm = 16; mm; mm >>= 1) acc += __shfl_xor(acc, mm, 64);
  if (lane32 == 0) {
    float md = __uint_as_float(*maxbits);
    float z = dinv[i] * acc + b2[0];
    float sc = 1.0f / (1.0f + expf(-z));
    out[i] = sc * (1.0f + dw[i] / md);
  }
}

extern "C" void kernel_launch(void* const* d_in, const int* in_sizes, int n_in,
                              void* d_out, int out_size, void* d_ws, size_t ws_size,
                              hipStream_t stream) {
  const float* x  = (const float*)d_in[0];
  const int*   ei = (const int*)d_in[1];
  const float* ew = (const float*)d_in[2];
  const float* W1 = (const float*)d_in[3];
  const float* b1 = (const float*)d_in[4];
  const float* W2 = (const float*)d_in[5];
  const float* b2 = (const float*)d_in[6];
  float* out = (float*)d_out;

  int N = out_size;      // 100000
  int E = in_sizes[2];   // 3200000
  const int* src = ei;
  const int* dst = ei + E;

  int NBD = (N + BSZ - 1) >> BSH;       // 782
  int NBS = (N + BSZS - 1) >> BSHS;     // 98
  int TOT = (NBD + NBS) * NWG;          // 225280
  int SB = (TOT + 1023) >> 10;          // 220
  size_t shmem = (size_t)(NBD + NBS) * sizeof(int);

  char* w8 = (char*)d_ws;
  int2*     gD      = (int2*)w8;                         // E int2  (becomes CSR in place)
  unsigned* gS      = (unsigned*)(gD + E);               // E u32
  int*      cntAll  = (int*)(gS + E);                    // TOT i  (scanned in place)
  int*      partials= cntAll + TOT;                      // 1024 i
  int*      off     = partials + 1024;                   // N+1 i
  float*    dinv    = (float*)(off + N + 1);             // N f
  float*    dw      = dinv + N;                          // N f
  float*    u       = dw + N;                            // N f
  unsigned* maxbits = (unsigned*)(u + N);                // 1 u
  unsigned char* g0 = (unsigned char*)(maxbits + 2);     // N*64 fp8

  k_count<<<NWG, PT, shmem, stream>>>(src, dst, cntAll, NBD, NBS, E);
  k_scanA<<<SB, 1024, 0, stream>>>(cntAll, partials, TOT);
  k_scanB<<<1, 1024, 0, stream>>>(partials, SB, maxbits);
  k_scanC<<<SB, 1024, 0, stream>>>(cntAll, partials, TOT);
  k_part<<<NWG, PT, shmem, stream>>>(src, dst, ew, cntAll, gD, gS, NBD, NBS, E);
  k_csr<<<NBD, 256, 0, stream>>>(gD, cntAll, off, dinv, NBD, N, E);
  k_dw<<<NBS, BSZS, 0, stream>>>(gS, cntAll, dw, maxbits, NBD, NBS, N, E);
  k_gemm1<<<256, 256, 0, stream>>>(x, W1, dinv, g0, N);
  k_agg1<<<(N * 64 + 255) / 256, 256, 0, stream>>>(g0, dinv, off, gD, b1, W2, u, N);
  k_agg2_final<<<(N + 7) / 8, 256, 0, stream>>>(u, dinv, off, gD, b2, dw, maxbits, out, N);
}